// Round 2
// baseline (311.100 us; speedup 1.0000x reference)
//
#include <hip/hip_runtime.h>
#include <hip/hip_bf16.h>

// Problem: B=4, L=4096, DH=1024, T=1024, DG=768, P=256
// Inputs fp32 + bool mask (width auto-detect); OUTPUT fp32.
// Pipeline (softmax FUSED into the GEMMs — no standalone softmax pass):
//   memset Z, memset rowsum
//   w) mask width probe
//   0) h_prep: H fp32 -> Hbf [B*L,DH] + Ht [B,DH,L]; cvt G,Wk,Wq -> bf16
//   1) Qbf = Gbf @ Wqbf^T            [B*T, P]   bf16
//   2) Kbf = Hbf @ Wkbf^T            [B*L, P]   bf16
//   3) P   = exp(Qbf @ Kbf^T / 16) masked->0    [B, T, L] bf16 (UNNORMALIZED)
//      + rowsum[b,t] += sum_l P  (fp32 atomics, from bf16-rounded P)
//   4) Z  += (P @ Ht^T) * (1/rowsum[row])   split-K x4, fp32 atomicAdd
// GEMM K-loop: DOUBLE-BUFFERED global_load_lds prefetch (one barrier/iter).
// LDS tiles use a GRANULE-XOR swizzle (rule 21: linear LDS dest, inverse-
// swizzled GLOBAL source, swizzled ds_read): granule g of row r stored at
// g ^ ((r>>1)&3). Kills the 16-extra-cycles/ds_read_b128 bank conflict
// (SQ_LDS_BANK_CONFLICT was exactly 16 x wave-reads with the linear layout:
// within a 32-lane phase hi spans {0,1} only -> 4 of 8 bank groups used).
// All GEMMs use XCD-chunked blockIdx swizzle (T1) for per-XCD L2 reuse.

typedef __attribute__((ext_vector_type(8))) short short8;   // 8 bf16 = 4 VGPRs
typedef __attribute__((ext_vector_type(4))) float f32x4;

static __device__ __forceinline__ unsigned short bf16bits(float x) {
    __hip_bfloat16 b = __float2bfloat16(x);
    return *(unsigned short*)&b;
}

// Async global->LDS, 16 B per lane. LDS dest = wave-uniform base + lane*16.
static __device__ __forceinline__ void gload_lds16(const __hip_bfloat16* g,
                                                   __hip_bfloat16* l)
{
    auto gp = (const __attribute__((address_space(1))) unsigned int*)(uintptr_t)g;
    auto lp = (__attribute__((address_space(3))) unsigned int*)(unsigned int)(uintptr_t)l;
    __builtin_amdgcn_global_load_lds(gp, lp, 16, 0, 0);
}

// ---------------------------------------------------------------------------
__global__ __launch_bounds__(256)
void cvt_f32_bf16_kernel(const float* __restrict__ in,
                         unsigned short* __restrict__ out, int n4)
{
    const int i = blockIdx.x * 256 + threadIdx.x;
    if (i >= n4) return;
    float4 v = ((const float4*)in)[i];
    ushort4 o;
    o.x = bf16bits(v.x); o.y = bf16bits(v.y);
    o.z = bf16bits(v.z); o.w = bf16bits(v.w);
    ((ushort4*)out)[i] = o;
}

// ---------------------------------------------------------------------------
// H prep: one read of H fp32 -> Hbf (row-major bf16) + Ht (transpose bf16).
// ---------------------------------------------------------------------------
__global__ __launch_bounds__(256)
void h_prep_kernel(const float* __restrict__ H,
                   __hip_bfloat16* __restrict__ Hbf,
                   __hip_bfloat16* __restrict__ Ht, int L, int D)
{
    const long b = blockIdx.z;
    const float* Hb = H + b * (long)L * D;
    __hip_bfloat16* Hbfb = Hbf + b * (long)L * D;
    __hip_bfloat16* Htb  = Ht  + b * (long)D * L;
    __shared__ float tile[32][33];
    const int l0 = blockIdx.x * 32, d0 = blockIdx.y * 32;
    const int tx = threadIdx.x & 31, ty = threadIdx.x >> 5;  // 32 x 8
    #pragma unroll
    for (int j = 0; j < 4; ++j) {
        const float v = Hb[(long)(l0 + ty + j * 8) * D + d0 + tx];
        tile[ty + j * 8][tx] = v;
        Hbfb[(long)(l0 + ty + j * 8) * D + d0 + tx] = __float2bfloat16(v);
    }
    __syncthreads();
    #pragma unroll
    for (int j = 0; j < 4; ++j)
        Htb[(long)(d0 + ty + j * 8) * L + l0 + tx] = __float2bfloat16(tile[tx][ty + j * 8]);
}

// ---------------------------------------------------------------------------
// GEMM: C[M,N] (op)= scale * A[M,K] @ Bm[N,K]^T  (bf16 row-major, K contig)
// 128x128 tile, 4 waves, wave 64x64 via 4x4 MFMA 16x16x32 bf16.
// DOUBLE-BUFFERED staging via global_load_lds width=16 into As/Bs[2][128][32].
// Granule-XOR LDS swizzle (see header comment).
// MODE 0: plain store (OutT bf16 or f32), scaled.
// MODE 2: P = exp(scale*acc), masked cols -> 0; store bf16; accumulate fp32
//         row-sums (from the bf16-ROUNDED values).
// MODE 3: atomicAdd(C, acc * (1/rowsum[row])) — fused softmax normalize.
// ---------------------------------------------------------------------------
template <typename OutT, int SPLITK, int MODE>
__global__ __launch_bounds__(256)
void gemm_bt_kernel(const __hip_bfloat16* __restrict__ A,
                    const __hip_bfloat16* __restrict__ Bm,
                    OutT* __restrict__ C,
                    int K, int lda, int ldb, int ldc,
                    long batchStrideA, long batchStrideB, long batchStrideC,
                    float scale,
                    const unsigned char* __restrict__ mask,
                    const int* __restrict__ widthPtr,
                    float* __restrict__ rowsum,
                    int rowsumStride)
{
    // XCD-chunked swizzle (T1): HW round-robins consecutive ids over 8 XCDs;
    // remap so each XCD owns a CONTIGUOUS chunk of tile space (L2 reuse).
    int bx = blockIdx.x, by = blockIdx.y, bz = blockIdx.z;
    {
        const int nwg = gridDim.x * gridDim.y * gridDim.z;
        if ((nwg & 7) == 0) {
            int lin = bx + gridDim.x * (by + gridDim.y * bz);
            lin = (lin & 7) * (nwg >> 3) + (lin >> 3);
            bx = lin % gridDim.x;
            const int t = lin / gridDim.x;
            by = t % gridDim.y;
            bz = t / gridDim.y;
        }
    }

    const int zb = bz / SPLITK;
    const int kc = bz % SPLITK;
    A  += (long)zb * batchStrideA;
    Bm += (long)zb * batchStrideB;
    C  += (long)zb * batchStrideC;
    const int Kloc  = K / SPLITK;
    const int kbase = kc * Kloc;

    const int tid  = threadIdx.x;
    const int lane = tid & 63;
    const int wave = tid >> 6;
    const int wm = (wave & 1) * 64;
    const int wn = (wave >> 1) * 64;
    const int rowBase = bx * 128;
    const int colBase = by * 128;

    __shared__ __hip_bfloat16 As[2][128][32];   // unpadded: global_load_lds layout
    __shared__ __hip_bfloat16 Bs[2][128][32];

    f32x4 acc[4][4];
    #pragma unroll
    for (int i = 0; i < 4; ++i)
        #pragma unroll
        for (int j = 0; j < 4; ++j)
            acc[i][j] = (f32x4){0.f, 0.f, 0.f, 0.f};

    // Staging: wave w covers rows [w*32, w*32+32) as two 16-row x 1024 B chunks.
    // Lane i: LDS lands at (row = i>>2, granule g = i&3). Pre-swizzle the
    // GLOBAL source granule: q = g ^ ((row>>1)&3)  (involution per row).
    const int srow = lane >> 2;
    const int scol = ((lane & 3) ^ ((lane >> 3) & 3)) * 8;   // swizzled source col
    const long ar0 = (long)(rowBase + wave * 32 + srow) * lda;
    const long ar1 = ar0 + 16l * lda;
    const long br0 = (long)(colBase + wave * 32 + srow) * ldb;
    const long br1 = br0 + 16l * ldb;

    const int mrow = lane & 15;         // fragment m/n index
    // Swizzled fragment k-offset: logical granule hi=(lane>>4) of row mrow is
    // stored at hi ^ ((mrow>>1)&3). Row bases (wm, mi*16) are ≡0 mod 16 so the
    // row-dependent term depends only on the lane id — compute once.
    const int koff = (((lane >> 4) ^ ((lane >> 1) & 3)) * 8);

    // Prologue: tile 0 -> buffer 0
    {
        const int kk = kbase + scol;
        gload_lds16(A  + ar0 + kk, &As[0][wave * 32][0]);
        gload_lds16(A  + ar1 + kk, &As[0][wave * 32 + 16][0]);
        gload_lds16(Bm + br0 + kk, &Bs[0][wave * 32][0]);
        gload_lds16(Bm + br1 + kk, &Bs[0][wave * 32 + 16][0]);
    }

    int cur = 0;
    for (int k0 = 0; k0 < Kloc; k0 += 32) {
        __syncthreads();   // drains vmcnt: buf[cur] ready; prev ds_reads done
        if (k0 + 32 < Kloc) {
            const int kk = kbase + k0 + 32 + scol;
            const int nxt = cur ^ 1;
            gload_lds16(A  + ar0 + kk, &As[nxt][wave * 32][0]);
            gload_lds16(A  + ar1 + kk, &As[nxt][wave * 32 + 16][0]);
            gload_lds16(Bm + br0 + kk, &Bs[nxt][wave * 32][0]);
            gload_lds16(Bm + br1 + kk, &Bs[nxt][wave * 32 + 16][0]);
        }

        short8 af[4], bf[4];
        #pragma unroll
        for (int mi = 0; mi < 4; ++mi)
            af[mi] = *(const short8*)(&As[cur][wm + mi * 16 + mrow][koff]);
        #pragma unroll
        for (int ni = 0; ni < 4; ++ni)
            bf[ni] = *(const short8*)(&Bs[cur][wn + ni * 16 + mrow][koff]);

        #pragma unroll
        for (int mi = 0; mi < 4; ++mi)
            #pragma unroll
            for (int ni = 0; ni < 4; ++ni)
                acc[mi][ni] = __builtin_amdgcn_mfma_f32_16x16x32_bf16(
                    af[mi], bf[ni], acc[mi][ni], 0, 0, 0);
        cur ^= 1;
    }

    // C/D layout (verified m89/m91): col = lane&15, row = (lane>>4)*4 + r
    const int crow0 = (lane >> 4) * 4;
    const int ccol  = lane & 15;

    if constexpr (MODE == 2) {
        // masked exp epilogue + fp32 row-sum accumulation
        const int w = *widthPtr;
        const long mbase = (long)zb * ldc;     // mask row length == ldc == L
        bool mk[4];
        #pragma unroll
        for (int ni = 0; ni < 4; ++ni) {
            const long midx = mbase + colBase + wn + ni * 16 + ccol;
            if (w == 1)      mk[ni] = mask[midx] != 0;
            else if (w == 2) mk[ni] = ((const unsigned short*)mask)[midx] != 0;
            else if (w == 4) mk[ni] = ((const unsigned int*)mask)[midx] != 0;
            else { uint2 q = ((const uint2*)mask)[midx]; mk[ni] = (q.x | q.y) != 0; }
        }
        #pragma unroll
        for (int mi = 0; mi < 4; ++mi) {
            #pragma unroll
            for (int r = 0; r < 4; ++r) {
                const int row = rowBase + wm + mi * 16 + crow0 + r;
                float rs = 0.f;
                #pragma unroll
                for (int ni = 0; ni < 4; ++ni) {
                    const int col = colBase + wn + ni * 16 + ccol;
                    const float e = mk[ni] ? 0.f
                                           : __expf(acc[mi][ni][r] * scale);
                    const __hip_bfloat16 pb = __float2bfloat16(e);
                    C[(long)row * ldc + col] = pb;
                    rs += __bfloat162float(pb);
                }
                // reduce over the 16 lanes sharing this row (distinct ccols)
                rs += __shfl_xor(rs, 1, 64);
                rs += __shfl_xor(rs, 2, 64);
                rs += __shfl_xor(rs, 4, 64);
                rs += __shfl_xor(rs, 8, 64);
                if ((lane & 15) == 0)
                    atomicAdd(&rowsum[(long)zb * rowsumStride + row], rs);
            }
        }
    } else if constexpr (MODE == 3) {
        // split-K atomic accumulate with fused 1/rowsum normalization
        #pragma unroll
        for (int mi = 0; mi < 4; ++mi) {
            #pragma unroll
            for (int r = 0; r < 4; ++r) {
                const int row = rowBase + wm + mi * 16 + crow0 + r;
                const float inv = 1.0f / rowsum[(long)zb * rowsumStride + row];
                #pragma unroll
                for (int ni = 0; ni < 4; ++ni) {
                    const int col = colBase + wn + ni * 16 + ccol;
                    atomicAdd(&((float*)C)[(long)row * ldc + col],
                              acc[mi][ni][r] * inv);
                }
            }
        }
    } else {
        #pragma unroll
        for (int mi = 0; mi < 4; ++mi) {
            #pragma unroll
            for (int ni = 0; ni < 4; ++ni) {
                #pragma unroll
                for (int r = 0; r < 4; ++r) {
                    const int row = rowBase + wm + mi * 16 + crow0 + r;
                    const int col = colBase + wn + ni * 16 + ccol;
                    const float v = acc[mi][ni][r] * scale;
                    if constexpr (sizeof(OutT) == 2)
                        C[(long)row * ldc + col] = __float2bfloat16(v);
                    else
                        C[(long)row * ldc + col] = v;
                }
            }
        }
    }
}

// ---------------------------------------------------------------------------
// Mask element-width detector (16384 bools, ~50% True).
// ---------------------------------------------------------------------------
__global__ __launch_bounds__(256)
void mask_width_kernel(const unsigned char* __restrict__ m, int* __restrict__ widthOut)
{
    __shared__ int c1, c2, c4, c8, cp;
    if (threadIdx.x == 0) { c1 = c2 = c4 = c8 = cp = 0; }
    __syncthreads();
    int l1 = 0, l2 = 0, l4 = 0, l8 = 0, lp = 0;
    const unsigned short* m16 = (const unsigned short*)m;
    const unsigned int*   m32 = (const unsigned int*)m;
    for (int i = threadIdx.x; i < 16384; i += 256) l1 += (m[i] != 0);
    for (int i = threadIdx.x; i < 8192;  i += 256) {
        l2 += (m16[i] != 0);
        lp += ((m[2 * i] != 0) == (m[2 * i + 1] != 0));
    }
    for (int i = threadIdx.x; i < 4096;  i += 256) l4 += (m32[i] != 0);
    for (int i = threadIdx.x; i < 2048;  i += 256) l8 += ((m32[2 * i] | m32[2 * i + 1]) != 0);
    atomicAdd(&c1, l1); atomicAdd(&c2, l2); atomicAdd(&c4, l4);
    atomicAdd(&c8, l8); atomicAdd(&cp, lp);
    __syncthreads();
    if (threadIdx.x == 0) {
        const float f1 = fabsf(c1 / 16384.f - 0.5f);
        const float f2 = fabsf(c2 / 8192.f  - 0.5f);
        const float f4 = fabsf(c4 / 4096.f  - 0.5f);
        const float f8 = fabsf(c8 / 2048.f  - 0.5f);
        int w = 1; float best = f1;
        if (f2 < best) { best = f2; w = 2; }
        if (f4 < best) { best = f4; w = 4; }
        if (f8 < best) { best = f8; w = 8; }
        if (w == 1 && cp > 7400) w = 2;
        *widthOut = w;
    }
}

// ---------------------------------------------------------------------------
extern "C" void kernel_launch(void* const* d_in, const int* in_sizes, int n_in,
                              void* d_out, int out_size, void* d_ws, size_t ws_size,
                              hipStream_t stream)
{
    constexpr int B = 4, L = 4096, DH = 1024, T = 1024, DG = 768, P = 256;

    const float* H  = (const float*)d_in[0];
    const float* G  = (const float*)d_in[1];
    const void*  mask = d_in[2];
    const float* Wk = (const float*)d_in[3];
    const float* Wq = (const float*)d_in[4];
    for (int i = 0; i < n_in; ++i) {
        switch (in_sizes[i]) {
            case B * L * DH: H    = (const float*)d_in[i]; break;
            case B * T * DG: G    = (const float*)d_in[i]; break;
            case B * L:      mask = d_in[i];               break;
            case P * DH:     Wk   = (const float*)d_in[i]; break;
            case P * DG:     Wq   = (const float*)d_in[i]; break;
        }
    }
    float* Z = (float*)d_out;

    char* ws = (char*)d_ws;
    __hip_bfloat16* Hbf  = (__hip_bfloat16*)ws;                      // [0, 32 MiB)
    __hip_bfloat16* Ht   = (__hip_bfloat16*)(ws + (32l << 20));      // [32, 64)
    __hip_bfloat16* Gbf  = (__hip_bfloat16*)(ws + (64l << 20));      // [64, 70)
    __hip_bfloat16* Qbf  = (__hip_bfloat16*)(ws + (70l << 20));      // [70, 72)
    __hip_bfloat16* Kbf  = (__hip_bfloat16*)(ws + (72l << 20));      // [72, 80)
    __hip_bfloat16* Wkbf = (__hip_bfloat16*)(ws + (80l << 20));      // 512 KiB
    __hip_bfloat16* Wqbf = (__hip_bfloat16*)(ws + (80l << 20) + (512l << 10)); // 384 KiB
    float*          rowsum    = (float*)(ws + (80l << 20) + (896l << 10));     // 64 KiB
    int*            widthFlag = (int*)  (ws + (80l << 20) + (960l << 10));     // 4 B
    __hip_bfloat16* Sb   = (__hip_bfloat16*)(ws + (81l << 20));      // [81, 113)

    const dim3 blk(256);

    // Zero the fp32 output (Z-pass accumulates via atomicAdd) + rowsums.
    hipMemsetAsync(d_out, 0, (size_t)out_size * sizeof(float), stream);
    hipMemsetAsync(rowsum, 0, (size_t)(B * T) * sizeof(float), stream);

    // w) mask width detection (must precede the fused S epilogue)
    mask_width_kernel<<<dim3(1), blk, 0, stream>>>((const unsigned char*)mask, widthFlag);

    // 0) input prep
    h_prep_kernel<<<dim3(L / 32, DH / 32, B), blk, 0, stream>>>(H, Hbf, Ht, L, DH);
    cvt_f32_bf16_kernel<<<dim3((P * DH) / 1024), blk, 0, stream>>>(Wk, (unsigned short*)Wkbf, (P * DH) / 4);
    cvt_f32_bf16_kernel<<<dim3((P * DG) / 1024), blk, 0, stream>>>(Wq, (unsigned short*)Wqbf, (P * DG) / 4);
    cvt_f32_bf16_kernel<<<dim3((B * T * DG) / 1024), blk, 0, stream>>>(G, (unsigned short*)Gbf, (B * T * DG) / 4);

    // 1) Q = G @ Wq^T   [B*T, P]
    gemm_bt_kernel<__hip_bfloat16, 1, 0><<<dim3((B * T) / 128, P / 128, 1), blk, 0, stream>>>(
        Gbf, Wqbf, Qbf, DG, DG, DG, P, 0, 0, 0, 1.0f,
        nullptr, nullptr, nullptr, 0);
    // 2) K = H @ Wk^T   [B*L, P]
    gemm_bt_kernel<__hip_bfloat16, 1, 0><<<dim3((B * L) / 128, P / 128, 1), blk, 0, stream>>>(
        Hbf, Wkbf, Kbf, DH, DH, DH, P, 0, 0, 0, 1.0f,
        nullptr, nullptr, nullptr, 0);
    // 3) P = exp(Q @ K^T * P^-0.5), masked -> 0; rowsum accumulate  [B,T,L]
    gemm_bt_kernel<__hip_bfloat16, 1, 2><<<dim3(T / 128, L / 128, B), blk, 0, stream>>>(
        Qbf, Kbf, Sb, P, P, P, L,
        (long)T * P, (long)L * P, (long)T * L, 0.0625f,
        (const unsigned char*)mask, widthFlag, rowsum, T);
    // 4) Z += (P @ Ht^T) / rowsum   split-K x4, fp32 atomic out
    gemm_bt_kernel<float, 4, 3><<<dim3(T / 128, DH / 128, B * 4), blk, 0, stream>>>(
        Sb, Ht, Z, L, L, L, DH,
        (long)T * L, (long)DH * L, (long)T * DH, 1.0f,
        nullptr, nullptr, rowsum, T);
}

// Round 3
// 272.436 us; speedup vs baseline: 1.1419x; 1.1419x over previous
//
#include <hip/hip_runtime.h>
#include <hip/hip_bf16.h>

// Problem: B=4, L=4096, DH=1024, T=1024, DG=768, P=256
// Inputs fp32 + bool mask (width auto-detect); OUTPUT fp32.
// Pipeline (softmax FUSED into the GEMMs — no standalone softmax pass):
//   memset Z, memset rowsum
//   w) mask width probe
//   0) h_prep: H fp32 -> Hbf [B*L,DH] + Ht [B,DH,L]; cvt G,Wk,Wq -> bf16
//   1) Qbf = Gbf @ Wqbf^T            [B*T, P]   bf16
//   2) Kbf = Hbf @ Wkbf^T            [B*L, P]   bf16
//   3) P   = exp(Qbf @ Kbf^T / 16) masked->0    [B, T, L] bf16 (UNNORMALIZED)
//      + rowsum[b,t] += sum_l P  (fp32 atomics, from bf16-rounded P)
//   4) Z  += (P @ Ht^T) * (1/rowsum[row])   split-K x2, fp32 atomicAdd
//
// GEMM K-loop: COUNTED-VMCNT pipeline (T4), 3 LDS buffers, prefetch depth 2.
// Per wave each tile = exactly 4 global_load_lds ops, so at iter top:
//   s_waitcnt vmcnt(4)  -> tile t drained, tile t+1's loads stay IN FLIGHT
//   s_barrier           -> all waves aligned (same per-wave discipline)
//   issue tile t+2      -> into buf[(t+2)%3] (read last at iter t-1: safe)
// Loads never drain to 0 in the main loop (m218 counted-vs-drain0 lever).
// LDS tiles keep the GRANULE-XOR swizzle from round 2 (conflicts == 0,
// verified): linear LDS dest, inverse-swizzled GLOBAL source, swizzled
// ds_read (granule g of row r at g ^ ((r>>1)&3)).
// All GEMMs use XCD-chunked blockIdx swizzle (T1) for per-XCD L2 reuse.
// Z split-K = 2 (measured best: sk2 64.8us vs sk4 90us).

typedef __attribute__((ext_vector_type(8))) short short8;   // 8 bf16 = 4 VGPRs
typedef __attribute__((ext_vector_type(4))) float f32x4;

static __device__ __forceinline__ unsigned short bf16bits(float x) {
    __hip_bfloat16 b = __float2bfloat16(x);
    return *(unsigned short*)&b;
}

// Async global->LDS, 16 B per lane. LDS dest = wave-uniform base + lane*16.
static __device__ __forceinline__ void gload_lds16(const __hip_bfloat16* g,
                                                   __hip_bfloat16* l)
{
    auto gp = (const __attribute__((address_space(1))) unsigned int*)(uintptr_t)g;
    auto lp = (__attribute__((address_space(3))) unsigned int*)(unsigned int)(uintptr_t)l;
    __builtin_amdgcn_global_load_lds(gp, lp, 16, 0, 0);
}

// ---------------------------------------------------------------------------
__global__ __launch_bounds__(256)
void cvt_f32_bf16_kernel(const float* __restrict__ in,
                         unsigned short* __restrict__ out, int n4)
{
    const int i = blockIdx.x * 256 + threadIdx.x;
    if (i >= n4) return;
    float4 v = ((const float4*)in)[i];
    ushort4 o;
    o.x = bf16bits(v.x); o.y = bf16bits(v.y);
    o.z = bf16bits(v.z); o.w = bf16bits(v.w);
    ((ushort4*)out)[i] = o;
}

// ---------------------------------------------------------------------------
// H prep: one read of H fp32 -> Hbf (row-major bf16) + Ht (transpose bf16).
// ---------------------------------------------------------------------------
__global__ __launch_bounds__(256)
void h_prep_kernel(const float* __restrict__ H,
                   __hip_bfloat16* __restrict__ Hbf,
                   __hip_bfloat16* __restrict__ Ht, int L, int D)
{
    const long b = blockIdx.z;
    const float* Hb = H + b * (long)L * D;
    __hip_bfloat16* Hbfb = Hbf + b * (long)L * D;
    __hip_bfloat16* Htb  = Ht  + b * (long)D * L;
    __shared__ float tile[32][33];
    const int l0 = blockIdx.x * 32, d0 = blockIdx.y * 32;
    const int tx = threadIdx.x & 31, ty = threadIdx.x >> 5;  // 32 x 8
    #pragma unroll
    for (int j = 0; j < 4; ++j) {
        const float v = Hb[(long)(l0 + ty + j * 8) * D + d0 + tx];
        tile[ty + j * 8][tx] = v;
        Hbfb[(long)(l0 + ty + j * 8) * D + d0 + tx] = __float2bfloat16(v);
    }
    __syncthreads();
    #pragma unroll
    for (int j = 0; j < 4; ++j)
        Htb[(long)(d0 + ty + j * 8) * L + l0 + tx] = __float2bfloat16(tile[tx][ty + j * 8]);
}

// ---------------------------------------------------------------------------
// GEMM: C[M,N] (op)= scale * A[M,K] @ Bm[N,K]^T  (bf16 row-major, K contig)
// 128x128 tile, 4 waves, wave 64x64 via 4x4 MFMA 16x16x32 bf16.
// Counted-vmcnt 3-buffer pipeline (see file header).
// MODE 0: plain store (OutT bf16 or f32), scaled.
// MODE 2: P = exp(scale*acc), masked cols -> 0; store bf16; accumulate fp32
//         row-sums (from the bf16-ROUNDED values).
// MODE 3: atomicAdd(C, acc * (1/rowsum[row])) — fused softmax normalize.
// ---------------------------------------------------------------------------
template <typename OutT, int SPLITK, int MODE>
__global__ __launch_bounds__(256)
void gemm_bt_kernel(const __hip_bfloat16* __restrict__ A,
                    const __hip_bfloat16* __restrict__ Bm,
                    OutT* __restrict__ C,
                    int K, int lda, int ldb, int ldc,
                    long batchStrideA, long batchStrideB, long batchStrideC,
                    float scale,
                    const unsigned char* __restrict__ mask,
                    const int* __restrict__ widthPtr,
                    float* __restrict__ rowsum,
                    int rowsumStride)
{
    // XCD-chunked swizzle (T1): HW round-robins consecutive ids over 8 XCDs;
    // remap so each XCD owns a CONTIGUOUS chunk of tile space (L2 reuse).
    int bx = blockIdx.x, by = blockIdx.y, bz = blockIdx.z;
    {
        const int nwg = gridDim.x * gridDim.y * gridDim.z;
        if ((nwg & 7) == 0) {
            int lin = bx + gridDim.x * (by + gridDim.y * bz);
            lin = (lin & 7) * (nwg >> 3) + (lin >> 3);
            bx = lin % gridDim.x;
            const int t = lin / gridDim.x;
            by = t % gridDim.y;
            bz = t / gridDim.y;
        }
    }

    const int zb = bz / SPLITK;
    const int kc = bz % SPLITK;
    A  += (long)zb * batchStrideA;
    Bm += (long)zb * batchStrideB;
    C  += (long)zb * batchStrideC;
    const int Kloc  = K / SPLITK;
    const int kbase = kc * Kloc;
    const int NT    = Kloc / 32;          // k-tiles

    const int tid  = threadIdx.x;
    const int lane = tid & 63;
    const int wave = tid >> 6;
    const int wm = (wave & 1) * 64;
    const int wn = (wave >> 1) * 64;
    const int rowBase = bx * 128;
    const int colBase = by * 128;

    __shared__ __hip_bfloat16 As[3][128][32];   // 3 buffers: depth-2 prefetch
    __shared__ __hip_bfloat16 Bs[3][128][32];

    f32x4 acc[4][4];
    #pragma unroll
    for (int i = 0; i < 4; ++i)
        #pragma unroll
        for (int j = 0; j < 4; ++j)
            acc[i][j] = (f32x4){0.f, 0.f, 0.f, 0.f};

    // Staging: wave w covers rows [w*32, w*32+32) as two 16-row x 1024 B chunks.
    // Lane i: LDS lands at (row = i>>2, granule g = i&3). Pre-swizzle the
    // GLOBAL source granule: q = g ^ ((row>>1)&3)  (involution per row).
    const int srow = lane >> 2;
    const int scol = ((lane & 3) ^ ((lane >> 3) & 3)) * 8;   // swizzled source col
    const long ar0 = (long)(rowBase + wave * 32 + srow) * lda;
    const long ar1 = ar0 + 16l * lda;
    const long br0 = (long)(colBase + wave * 32 + srow) * ldb;
    const long br1 = br0 + 16l * ldb;

    const int mrow = lane & 15;         // fragment m/n index
    // Swizzled fragment k-offset: logical granule hi=(lane>>4) of row mrow is
    // stored at hi ^ ((mrow>>1)&3). Row bases are ≡0 mod 16 so the row term
    // depends only on the lane id — compute once.
    const int koff = (((lane >> 4) ^ ((lane >> 1) & 3)) * 8);

    // Per wave each tile issues EXACTLY 4 global_load_lds ops (vmcnt units).
    auto stage = [&](int buf, int t) {
        const int kk = kbase + t * 32 + scol;
        gload_lds16(A  + ar0 + kk, &As[buf][wave * 32][0]);
        gload_lds16(A  + ar1 + kk, &As[buf][wave * 32 + 16][0]);
        gload_lds16(Bm + br0 + kk, &Bs[buf][wave * 32][0]);
        gload_lds16(Bm + br1 + kk, &Bs[buf][wave * 32 + 16][0]);
    };

    // Prologue: tiles 0,1 in flight (8 vmcnt ops/wave). No barrier yet.
    stage(0, 0);
    if (NT > 1) stage(1, 1);

    int cur = 0;
    for (int t = 0; t < NT; ++t) {
        // Drain OWN tile-t loads only; tile t+1 stays in flight across the
        // barrier (counted vmcnt — never drain to 0 in the main loop).
        if (t + 1 < NT)
            asm volatile("s_waitcnt vmcnt(4)" ::: "memory");
        else
            asm volatile("s_waitcnt vmcnt(0)" ::: "memory");
        __builtin_amdgcn_s_barrier();
        // Issue tile t+2 into buf[(t+2)%3]: last read at iter t-1, and every
        // wave finished those ds_reads before reaching this barrier -> safe.
        if (t + 2 < NT) {
            const int nxt2 = (cur >= 1) ? cur - 1 : cur + 2;   // (cur+2)%3
            stage(nxt2, t + 2);
        }

        short8 af[4], bf[4];
        #pragma unroll
        for (int mi = 0; mi < 4; ++mi)
            af[mi] = *(const short8*)(&As[cur][wm + mi * 16 + mrow][koff]);
        #pragma unroll
        for (int ni = 0; ni < 4; ++ni)
            bf[ni] = *(const short8*)(&Bs[cur][wn + ni * 16 + mrow][koff]);

        #pragma unroll
        for (int mi = 0; mi < 4; ++mi)
            #pragma unroll
            for (int ni = 0; ni < 4; ++ni)
                acc[mi][ni] = __builtin_amdgcn_mfma_f32_16x16x32_bf16(
                    af[mi], bf[ni], acc[mi][ni], 0, 0, 0);
        cur = (cur == 2) ? 0 : cur + 1;
    }

    // C/D layout (verified m89/m91): col = lane&15, row = (lane>>4)*4 + r
    const int crow0 = (lane >> 4) * 4;
    const int ccol  = lane & 15;

    if constexpr (MODE == 2) {
        // masked exp epilogue + fp32 row-sum accumulation
        const int w = *widthPtr;
        const long mbase = (long)zb * ldc;     // mask row length == ldc == L
        bool mk[4];
        #pragma unroll
        for (int ni = 0; ni < 4; ++ni) {
            const long midx = mbase + colBase + wn + ni * 16 + ccol;
            if (w == 1)      mk[ni] = mask[midx] != 0;
            else if (w == 2) mk[ni] = ((const unsigned short*)mask)[midx] != 0;
            else if (w == 4) mk[ni] = ((const unsigned int*)mask)[midx] != 0;
            else { uint2 q = ((const uint2*)mask)[midx]; mk[ni] = (q.x | q.y) != 0; }
        }
        #pragma unroll
        for (int mi = 0; mi < 4; ++mi) {
            #pragma unroll
            for (int r = 0; r < 4; ++r) {
                const int row = rowBase + wm + mi * 16 + crow0 + r;
                float rs = 0.f;
                #pragma unroll
                for (int ni = 0; ni < 4; ++ni) {
                    const int col = colBase + wn + ni * 16 + ccol;
                    const float e = mk[ni] ? 0.f
                                           : __expf(acc[mi][ni][r] * scale);
                    const __hip_bfloat16 pb = __float2bfloat16(e);
                    C[(long)row * ldc + col] = pb;
                    rs += __bfloat162float(pb);
                }
                // reduce over the 16 lanes sharing this row (distinct ccols)
                rs += __shfl_xor(rs, 1, 64);
                rs += __shfl_xor(rs, 2, 64);
                rs += __shfl_xor(rs, 4, 64);
                rs += __shfl_xor(rs, 8, 64);
                if ((lane & 15) == 0)
                    atomicAdd(&rowsum[(long)zb * rowsumStride + row], rs);
            }
        }
    } else if constexpr (MODE == 3) {
        // split-K atomic accumulate with fused 1/rowsum normalization
        #pragma unroll
        for (int mi = 0; mi < 4; ++mi) {
            #pragma unroll
            for (int r = 0; r < 4; ++r) {
                const int row = rowBase + wm + mi * 16 + crow0 + r;
                const float inv = 1.0f / rowsum[(long)zb * rowsumStride + row];
                #pragma unroll
                for (int ni = 0; ni < 4; ++ni) {
                    const int col = colBase + wn + ni * 16 + ccol;
                    atomicAdd(&((float*)C)[(long)row * ldc + col],
                              acc[mi][ni][r] * inv);
                }
            }
        }
    } else {
        #pragma unroll
        for (int mi = 0; mi < 4; ++mi) {
            #pragma unroll
            for (int ni = 0; ni < 4; ++ni) {
                #pragma unroll
                for (int r = 0; r < 4; ++r) {
                    const int row = rowBase + wm + mi * 16 + crow0 + r;
                    const int col = colBase + wn + ni * 16 + ccol;
                    const float v = acc[mi][ni][r] * scale;
                    if constexpr (sizeof(OutT) == 2)
                        C[(long)row * ldc + col] = __float2bfloat16(v);
                    else
                        C[(long)row * ldc + col] = v;
                }
            }
        }
    }
}

// ---------------------------------------------------------------------------
// Mask element-width detector (16384 bools, ~50% True).
// ---------------------------------------------------------------------------
__global__ __launch_bounds__(256)
void mask_width_kernel(const unsigned char* __restrict__ m, int* __restrict__ widthOut)
{
    __shared__ int c1, c2, c4, c8, cp;
    if (threadIdx.x == 0) { c1 = c2 = c4 = c8 = cp = 0; }
    __syncthreads();
    int l1 = 0, l2 = 0, l4 = 0, l8 = 0, lp = 0;
    const unsigned short* m16 = (const unsigned short*)m;
    const unsigned int*   m32 = (const unsigned int*)m;
    for (int i = threadIdx.x; i < 16384; i += 256) l1 += (m[i] != 0);
    for (int i = threadIdx.x; i < 8192;  i += 256) {
        l2 += (m16[i] != 0);
        lp += ((m[2 * i] != 0) == (m[2 * i + 1] != 0));
    }
    for (int i = threadIdx.x; i < 4096;  i += 256) l4 += (m32[i] != 0);
    for (int i = threadIdx.x; i < 2048;  i += 256) l8 += ((m32[2 * i] | m32[2 * i + 1]) != 0);
    atomicAdd(&c1, l1); atomicAdd(&c2, l2); atomicAdd(&c4, l4);
    atomicAdd(&c8, l8); atomicAdd(&cp, lp);
    __syncthreads();
    if (threadIdx.x == 0) {
        const float f1 = fabsf(c1 / 16384.f - 0.5f);
        const float f2 = fabsf(c2 / 8192.f  - 0.5f);
        const float f4 = fabsf(c4 / 4096.f  - 0.5f);
        const float f8 = fabsf(c8 / 2048.f  - 0.5f);
        int w = 1; float best = f1;
        if (f2 < best) { best = f2; w = 2; }
        if (f4 < best) { best = f4; w = 4; }
        if (f8 < best) { best = f8; w = 8; }
        if (w == 1 && cp > 7400) w = 2;
        *widthOut = w;
    }
}

// ---------------------------------------------------------------------------
extern "C" void kernel_launch(void* const* d_in, const int* in_sizes, int n_in,
                              void* d_out, int out_size, void* d_ws, size_t ws_size,
                              hipStream_t stream)
{
    constexpr int B = 4, L = 4096, DH = 1024, T = 1024, DG = 768, P = 256;

    const float* H  = (const float*)d_in[0];
    const float* G  = (const float*)d_in[1];
    const void*  mask = d_in[2];
    const float* Wk = (const float*)d_in[3];
    const float* Wq = (const float*)d_in[4];
    for (int i = 0; i < n_in; ++i) {
        switch (in_sizes[i]) {
            case B * L * DH: H    = (const float*)d_in[i]; break;
            case B * T * DG: G    = (const float*)d_in[i]; break;
            case B * L:      mask = d_in[i];               break;
            case P * DH:     Wk   = (const float*)d_in[i]; break;
            case P * DG:     Wq   = (const float*)d_in[i]; break;
        }
    }
    float* Z = (float*)d_out;

    char* ws = (char*)d_ws;
    __hip_bfloat16* Hbf  = (__hip_bfloat16*)ws;                      // [0, 32 MiB)
    __hip_bfloat16* Ht   = (__hip_bfloat16*)(ws + (32l << 20));      // [32, 64)
    __hip_bfloat16* Gbf  = (__hip_bfloat16*)(ws + (64l << 20));      // [64, 70)
    __hip_bfloat16* Qbf  = (__hip_bfloat16*)(ws + (70l << 20));      // [70, 72)
    __hip_bfloat16* Kbf  = (__hip_bfloat16*)(ws + (72l << 20));      // [72, 80)
    __hip_bfloat16* Wkbf = (__hip_bfloat16*)(ws + (80l << 20));      // 512 KiB
    __hip_bfloat16* Wqbf = (__hip_bfloat16*)(ws + (80l << 20) + (512l << 10)); // 384 KiB
    float*          rowsum    = (float*)(ws + (80l << 20) + (896l << 10));     // 64 KiB
    int*            widthFlag = (int*)  (ws + (80l << 20) + (960l << 10));     // 4 B
    __hip_bfloat16* Sb   = (__hip_bfloat16*)(ws + (81l << 20));      // [81, 113)

    const dim3 blk(256);

    // Zero the fp32 output (Z-pass accumulates via atomicAdd) + rowsums.
    hipMemsetAsync(d_out, 0, (size_t)out_size * sizeof(float), stream);
    hipMemsetAsync(rowsum, 0, (size_t)(B * T) * sizeof(float), stream);

    // w) mask width detection (must precede the fused S epilogue)
    mask_width_kernel<<<dim3(1), blk, 0, stream>>>((const unsigned char*)mask, widthFlag);

    // 0) input prep
    h_prep_kernel<<<dim3(L / 32, DH / 32, B), blk, 0, stream>>>(H, Hbf, Ht, L, DH);
    cvt_f32_bf16_kernel<<<dim3((P * DH) / 1024), blk, 0, stream>>>(Wk, (unsigned short*)Wkbf, (P * DH) / 4);
    cvt_f32_bf16_kernel<<<dim3((P * DG) / 1024), blk, 0, stream>>>(Wq, (unsigned short*)Wqbf, (P * DG) / 4);
    cvt_f32_bf16_kernel<<<dim3((B * T * DG) / 1024), blk, 0, stream>>>(G, (unsigned short*)Gbf, (B * T * DG) / 4);

    // 1) Q = G @ Wq^T   [B*T, P]
    gemm_bt_kernel<__hip_bfloat16, 1, 0><<<dim3((B * T) / 128, P / 128, 1), blk, 0, stream>>>(
        Gbf, Wqbf, Qbf, DG, DG, DG, P, 0, 0, 0, 1.0f,
        nullptr, nullptr, nullptr, 0);
    // 2) K = H @ Wk^T   [B*L, P]
    gemm_bt_kernel<__hip_bfloat16, 1, 0><<<dim3((B * L) / 128, P / 128, 1), blk, 0, stream>>>(
        Hbf, Wkbf, Kbf, DH, DH, DH, P, 0, 0, 0, 1.0f,
        nullptr, nullptr, nullptr, 0);
    // 3) P = exp(Q @ K^T * P^-0.5), masked -> 0; rowsum accumulate  [B,T,L]
    gemm_bt_kernel<__hip_bfloat16, 1, 2><<<dim3(T / 128, L / 128, B), blk, 0, stream>>>(
        Qbf, Kbf, Sb, P, P, P, L,
        (long)T * P, (long)L * P, (long)T * L, 0.0625f,
        (const unsigned char*)mask, widthFlag, rowsum, T);
    // 4) Z += (P @ Ht^T) / rowsum   split-K x2, fp32 atomic out
    gemm_bt_kernel<float, 2, 3><<<dim3(T / 128, DH / 128, B * 2), blk, 0, stream>>>(
        Sb, Ht, Z, L, L, L, DH,
        (long)T * L, (long)DH * L, (long)T * DH, 1.0f,
        nullptr, nullptr, rowsum, T);
}

// Round 4
// 260.840 us; speedup vs baseline: 1.1927x; 1.0445x over previous
//
#include <hip/hip_runtime.h>
#include <hip/hip_bf16.h>

// Problem: B=4, L=4096, DH=1024, T=1024, DG=768, P=256
// Inputs fp32 + bool mask (width auto-detect); OUTPUT fp32.
// Pipeline (softmax FUSED into the GEMMs — no standalone softmax pass):
//   memset rowsum
//   w) mask width probe
//   0) h_prep: H fp32 -> Hbf [B*L,DH] + Ht [B,DH,L]; cvt G,Wk,Wq -> bf16
//   1) Qbf = Gbf @ Wqbf^T            [B*T, P]   bf16
//   2) Kbf = Hbf @ Wkbf^T            [B*L, P]   bf16
//   3) P   = exp(Qbf @ Kbf^T / 16) masked->0    [B, T, L] bf16 (UNNORMALIZED)
//      + rowsum[b,t] += sum_l P  (fp32 atomics, from bf16-rounded P)
//   4) Zp[kc] = P @ Ht^T   split-K x2, PLAIN fp32 stores (NO atomics —
//      round-3 ablation: 16.8M epilogue atomicAdds were the Z bottleneck;
//      sk4->sk2 delta showed ~21us per 16.8M atomics)
//   5) Z = (Zp0 + Zp1) * (1/rowsum[row])  streaming combine, float4
//
// GEMM K-loop: COUNTED-VMCNT pipeline (T4), 3 LDS buffers, prefetch depth 2.
// Per wave each tile = exactly 4 global_load_lds ops, so at iter top:
//   s_waitcnt vmcnt(4)  -> tile t drained, tile t+1's loads stay IN FLIGHT
//   s_barrier           -> all waves aligned (same per-wave discipline)
//   issue tile t+2      -> into buf[(t+2)%3] (read last at iter t-1: safe)
// LDS tiles keep the GRANULE-XOR swizzle (conflicts == 0, verified):
// linear LDS dest, inverse-swizzled GLOBAL source, swizzled ds_read
// (granule g of row r at g ^ ((r>>1)&3)).
// All GEMMs use XCD-chunked blockIdx swizzle (T1) for per-XCD L2 reuse.

typedef __attribute__((ext_vector_type(8))) short short8;   // 8 bf16 = 4 VGPRs
typedef __attribute__((ext_vector_type(4))) float f32x4;

static __device__ __forceinline__ unsigned short bf16bits(float x) {
    __hip_bfloat16 b = __float2bfloat16(x);
    return *(unsigned short*)&b;
}

// Async global->LDS, 16 B per lane. LDS dest = wave-uniform base + lane*16.
static __device__ __forceinline__ void gload_lds16(const __hip_bfloat16* g,
                                                   __hip_bfloat16* l)
{
    auto gp = (const __attribute__((address_space(1))) unsigned int*)(uintptr_t)g;
    auto lp = (__attribute__((address_space(3))) unsigned int*)(unsigned int)(uintptr_t)l;
    __builtin_amdgcn_global_load_lds(gp, lp, 16, 0, 0);
}

// ---------------------------------------------------------------------------
__global__ __launch_bounds__(256)
void cvt_f32_bf16_kernel(const float* __restrict__ in,
                         unsigned short* __restrict__ out, int n4)
{
    const int i = blockIdx.x * 256 + threadIdx.x;
    if (i >= n4) return;
    float4 v = ((const float4*)in)[i];
    ushort4 o;
    o.x = bf16bits(v.x); o.y = bf16bits(v.y);
    o.z = bf16bits(v.z); o.w = bf16bits(v.w);
    ((ushort4*)out)[i] = o;
}

// ---------------------------------------------------------------------------
// H prep: one read of H fp32 -> Hbf (row-major bf16) + Ht (transpose bf16).
// ---------------------------------------------------------------------------
__global__ __launch_bounds__(256)
void h_prep_kernel(const float* __restrict__ H,
                   __hip_bfloat16* __restrict__ Hbf,
                   __hip_bfloat16* __restrict__ Ht, int L, int D)
{
    const long b = blockIdx.z;
    const float* Hb = H + b * (long)L * D;
    __hip_bfloat16* Hbfb = Hbf + b * (long)L * D;
    __hip_bfloat16* Htb  = Ht  + b * (long)D * L;
    __shared__ float tile[32][33];
    const int l0 = blockIdx.x * 32, d0 = blockIdx.y * 32;
    const int tx = threadIdx.x & 31, ty = threadIdx.x >> 5;  // 32 x 8
    #pragma unroll
    for (int j = 0; j < 4; ++j) {
        const float v = Hb[(long)(l0 + ty + j * 8) * D + d0 + tx];
        tile[ty + j * 8][tx] = v;
        Hbfb[(long)(l0 + ty + j * 8) * D + d0 + tx] = __float2bfloat16(v);
    }
    __syncthreads();
    #pragma unroll
    for (int j = 0; j < 4; ++j)
        Htb[(long)(d0 + ty + j * 8) * L + l0 + tx] = __float2bfloat16(tile[tx][ty + j * 8]);
}

// ---------------------------------------------------------------------------
// GEMM: C[M,N] (op)= scale * A[M,K] @ Bm[N,K]^T  (bf16 row-major, K contig)
// 128x128 tile, 4 waves, wave 64x64 via 4x4 MFMA 16x16x32 bf16.
// Counted-vmcnt 3-buffer pipeline (see file header).
// MODE 0: plain store (OutT bf16 or f32), scaled. With SPLITK>1 each kc
//         writes its own partial buffer at C + kc*partStride (no atomics).
// MODE 2: P = exp(scale*acc), masked cols -> 0; store bf16; accumulate fp32
//         row-sums (from the bf16-ROUNDED values).
// ---------------------------------------------------------------------------
template <typename OutT, int SPLITK, int MODE>
__global__ __launch_bounds__(256)
void gemm_bt_kernel(const __hip_bfloat16* __restrict__ A,
                    const __hip_bfloat16* __restrict__ Bm,
                    OutT* __restrict__ C,
                    int K, int lda, int ldb, int ldc,
                    long batchStrideA, long batchStrideB, long batchStrideC,
                    float scale,
                    const unsigned char* __restrict__ mask,
                    const int* __restrict__ widthPtr,
                    float* __restrict__ rowsum,
                    int rowsumStride,
                    long partStride)
{
    // XCD-chunked swizzle (T1): HW round-robins consecutive ids over 8 XCDs;
    // remap so each XCD owns a CONTIGUOUS chunk of tile space (L2 reuse).
    int bx = blockIdx.x, by = blockIdx.y, bz = blockIdx.z;
    {
        const int nwg = gridDim.x * gridDim.y * gridDim.z;
        if ((nwg & 7) == 0) {
            int lin = bx + gridDim.x * (by + gridDim.y * bz);
            lin = (lin & 7) * (nwg >> 3) + (lin >> 3);
            bx = lin % gridDim.x;
            const int t = lin / gridDim.x;
            by = t % gridDim.y;
            bz = t / gridDim.y;
        }
    }

    const int zb = bz / SPLITK;
    const int kc = bz % SPLITK;
    A  += (long)zb * batchStrideA;
    Bm += (long)zb * batchStrideB;
    C  += (long)zb * batchStrideC + (long)kc * partStride;
    const int Kloc  = K / SPLITK;
    const int kbase = kc * Kloc;
    const int NT    = Kloc / 32;          // k-tiles

    const int tid  = threadIdx.x;
    const int lane = tid & 63;
    const int wave = tid >> 6;
    const int wm = (wave & 1) * 64;
    const int wn = (wave >> 1) * 64;
    const int rowBase = bx * 128;
    const int colBase = by * 128;

    __shared__ __hip_bfloat16 As[3][128][32];   // 3 buffers: depth-2 prefetch
    __shared__ __hip_bfloat16 Bs[3][128][32];

    f32x4 acc[4][4];
    #pragma unroll
    for (int i = 0; i < 4; ++i)
        #pragma unroll
        for (int j = 0; j < 4; ++j)
            acc[i][j] = (f32x4){0.f, 0.f, 0.f, 0.f};

    // Staging: wave w covers rows [w*32, w*32+32) as two 16-row x 1024 B chunks.
    // Lane i: LDS lands at (row = i>>2, granule g = i&3). Pre-swizzle the
    // GLOBAL source granule: q = g ^ ((row>>1)&3)  (involution per row).
    const int srow = lane >> 2;
    const int scol = ((lane & 3) ^ ((lane >> 3) & 3)) * 8;   // swizzled source col
    const long ar0 = (long)(rowBase + wave * 32 + srow) * lda;
    const long ar1 = ar0 + 16l * lda;
    const long br0 = (long)(colBase + wave * 32 + srow) * ldb;
    const long br1 = br0 + 16l * ldb;

    const int mrow = lane & 15;         // fragment m/n index
    // Swizzled fragment k-offset: logical granule hi=(lane>>4) of row mrow is
    // stored at hi ^ ((mrow>>1)&3). Row bases are ≡0 mod 16 so the row term
    // depends only on the lane id — compute once.
    const int koff = (((lane >> 4) ^ ((lane >> 1) & 3)) * 8);

    // Per wave each tile issues EXACTLY 4 global_load_lds ops (vmcnt units).
    auto stage = [&](int buf, int t) {
        const int kk = kbase + t * 32 + scol;
        gload_lds16(A  + ar0 + kk, &As[buf][wave * 32][0]);
        gload_lds16(A  + ar1 + kk, &As[buf][wave * 32 + 16][0]);
        gload_lds16(Bm + br0 + kk, &Bs[buf][wave * 32][0]);
        gload_lds16(Bm + br1 + kk, &Bs[buf][wave * 32 + 16][0]);
    };

    // Prologue: tiles 0,1 in flight (8 vmcnt ops/wave). No barrier yet.
    stage(0, 0);
    if (NT > 1) stage(1, 1);

    int cur = 0;
    for (int t = 0; t < NT; ++t) {
        // Drain OWN tile-t loads only; tile t+1 stays in flight across the
        // barrier (counted vmcnt — never drain to 0 in the main loop).
        if (t + 1 < NT)
            asm volatile("s_waitcnt vmcnt(4)" ::: "memory");
        else
            asm volatile("s_waitcnt vmcnt(0)" ::: "memory");
        __builtin_amdgcn_s_barrier();
        // Issue tile t+2 into buf[(t+2)%3]: last read at iter t-1, and every
        // wave finished those ds_reads before reaching this barrier -> safe.
        if (t + 2 < NT) {
            const int nxt2 = (cur >= 1) ? cur - 1 : cur + 2;   // (cur+2)%3
            stage(nxt2, t + 2);
        }

        short8 af[4], bf[4];
        #pragma unroll
        for (int mi = 0; mi < 4; ++mi)
            af[mi] = *(const short8*)(&As[cur][wm + mi * 16 + mrow][koff]);
        #pragma unroll
        for (int ni = 0; ni < 4; ++ni)
            bf[ni] = *(const short8*)(&Bs[cur][wn + ni * 16 + mrow][koff]);

        #pragma unroll
        for (int mi = 0; mi < 4; ++mi)
            #pragma unroll
            for (int ni = 0; ni < 4; ++ni)
                acc[mi][ni] = __builtin_amdgcn_mfma_f32_16x16x32_bf16(
                    af[mi], bf[ni], acc[mi][ni], 0, 0, 0);
        cur = (cur == 2) ? 0 : cur + 1;
    }

    // C/D layout (verified m89/m91): col = lane&15, row = (lane>>4)*4 + r
    const int crow0 = (lane >> 4) * 4;
    const int ccol  = lane & 15;

    if constexpr (MODE == 2) {
        // masked exp epilogue + fp32 row-sum accumulation
        const int w = *widthPtr;
        const long mbase = (long)zb * ldc;     // mask row length == ldc == L
        bool mk[4];
        #pragma unroll
        for (int ni = 0; ni < 4; ++ni) {
            const long midx = mbase + colBase + wn + ni * 16 + ccol;
            if (w == 1)      mk[ni] = mask[midx] != 0;
            else if (w == 2) mk[ni] = ((const unsigned short*)mask)[midx] != 0;
            else if (w == 4) mk[ni] = ((const unsigned int*)mask)[midx] != 0;
            else { uint2 q = ((const uint2*)mask)[midx]; mk[ni] = (q.x | q.y) != 0; }
        }
        #pragma unroll
        for (int mi = 0; mi < 4; ++mi) {
            #pragma unroll
            for (int r = 0; r < 4; ++r) {
                const int row = rowBase + wm + mi * 16 + crow0 + r;
                float rs = 0.f;
                #pragma unroll
                for (int ni = 0; ni < 4; ++ni) {
                    const int col = colBase + wn + ni * 16 + ccol;
                    const float e = mk[ni] ? 0.f
                                           : __expf(acc[mi][ni][r] * scale);
                    const __hip_bfloat16 pb = __float2bfloat16(e);
                    C[(long)row * ldc + col] = pb;
                    rs += __bfloat162float(pb);
                }
                // reduce over the 16 lanes sharing this row (distinct ccols)
                rs += __shfl_xor(rs, 1, 64);
                rs += __shfl_xor(rs, 2, 64);
                rs += __shfl_xor(rs, 4, 64);
                rs += __shfl_xor(rs, 8, 64);
                if ((lane & 15) == 0)
                    atomicAdd(&rowsum[(long)zb * rowsumStride + row], rs);
            }
        }
    } else {
        #pragma unroll
        for (int mi = 0; mi < 4; ++mi) {
            #pragma unroll
            for (int ni = 0; ni < 4; ++ni) {
                #pragma unroll
                for (int r = 0; r < 4; ++r) {
                    const int row = rowBase + wm + mi * 16 + crow0 + r;
                    const int col = colBase + wn + ni * 16 + ccol;
                    const float v = acc[mi][ni][r] * scale;
                    if constexpr (sizeof(OutT) == 2)
                        C[(long)row * ldc + col] = __float2bfloat16(v);
                    else
                        C[(long)row * ldc + col] = v;
                }
            }
        }
    }
}

// ---------------------------------------------------------------------------
// Combine: Z = (Zp0 + Zp1) * (1/rowsum[row]).  Streaming, float4.
// n4 = B*T*DH/4 float4 elements; DH/4 = 256 float4 per row.
// ---------------------------------------------------------------------------
__global__ __launch_bounds__(256)
void combine_kernel(const float* __restrict__ Zp,
                    const float* __restrict__ rowsum,
                    float* __restrict__ Z, long partStride)
{
    const int i = blockIdx.x * 256 + threadIdx.x;   // float4 index
    const float4 a = ((const float4*)Zp)[i];
    const float4 b = ((const float4*)(Zp + partStride))[i];
    const float inv = 1.0f / rowsum[i >> 8];        // (4*i)/1024
    float4 o;
    o.x = (a.x + b.x) * inv;
    o.y = (a.y + b.y) * inv;
    o.z = (a.z + b.z) * inv;
    o.w = (a.w + b.w) * inv;
    ((float4*)Z)[i] = o;
}

// ---------------------------------------------------------------------------
// Mask element-width detector (16384 bools, ~50% True).
// ---------------------------------------------------------------------------
__global__ __launch_bounds__(256)
void mask_width_kernel(const unsigned char* __restrict__ m, int* __restrict__ widthOut)
{
    __shared__ int c1, c2, c4, c8, cp;
    if (threadIdx.x == 0) { c1 = c2 = c4 = c8 = cp = 0; }
    __syncthreads();
    int l1 = 0, l2 = 0, l4 = 0, l8 = 0, lp = 0;
    const unsigned short* m16 = (const unsigned short*)m;
    const unsigned int*   m32 = (const unsigned int*)m;
    for (int i = threadIdx.x; i < 16384; i += 256) l1 += (m[i] != 0);
    for (int i = threadIdx.x; i < 8192;  i += 256) {
        l2 += (m16[i] != 0);
        lp += ((m[2 * i] != 0) == (m[2 * i + 1] != 0));
    }
    for (int i = threadIdx.x; i < 4096;  i += 256) l4 += (m32[i] != 0);
    for (int i = threadIdx.x; i < 2048;  i += 256) l8 += ((m32[2 * i] | m32[2 * i + 1]) != 0);
    atomicAdd(&c1, l1); atomicAdd(&c2, l2); atomicAdd(&c4, l4);
    atomicAdd(&c8, l8); atomicAdd(&cp, lp);
    __syncthreads();
    if (threadIdx.x == 0) {
        const float f1 = fabsf(c1 / 16384.f - 0.5f);
        const float f2 = fabsf(c2 / 8192.f  - 0.5f);
        const float f4 = fabsf(c4 / 4096.f  - 0.5f);
        const float f8 = fabsf(c8 / 2048.f  - 0.5f);
        int w = 1; float best = f1;
        if (f2 < best) { best = f2; w = 2; }
        if (f4 < best) { best = f4; w = 4; }
        if (f8 < best) { best = f8; w = 8; }
        if (w == 1 && cp > 7400) w = 2;
        *widthOut = w;
    }
}

// ---------------------------------------------------------------------------
extern "C" void kernel_launch(void* const* d_in, const int* in_sizes, int n_in,
                              void* d_out, int out_size, void* d_ws, size_t ws_size,
                              hipStream_t stream)
{
    constexpr int B = 4, L = 4096, DH = 1024, T = 1024, DG = 768, P = 256;

    const float* H  = (const float*)d_in[0];
    const float* G  = (const float*)d_in[1];
    const void*  mask = d_in[2];
    const float* Wk = (const float*)d_in[3];
    const float* Wq = (const float*)d_in[4];
    for (int i = 0; i < n_in; ++i) {
        switch (in_sizes[i]) {
            case B * L * DH: H    = (const float*)d_in[i]; break;
            case B * T * DG: G    = (const float*)d_in[i]; break;
            case B * L:      mask = d_in[i];               break;
            case P * DH:     Wk   = (const float*)d_in[i]; break;
            case P * DG:     Wq   = (const float*)d_in[i]; break;
        }
    }
    float* Z = (float*)d_out;

    char* ws = (char*)d_ws;
    __hip_bfloat16* Hbf  = (__hip_bfloat16*)ws;                      // [0, 32 MiB) — dead after K-GEMM
    float*          Zp   = (float*)ws;                               // [0, 32 MiB): Zp0 16 MiB + Zp1 16 MiB (over dead Hbf)
    __hip_bfloat16* Ht   = (__hip_bfloat16*)(ws + (32l << 20));      // [32, 64)
    __hip_bfloat16* Gbf  = (__hip_bfloat16*)(ws + (64l << 20));      // [64, 70)
    __hip_bfloat16* Qbf  = (__hip_bfloat16*)(ws + (70l << 20));      // [70, 72)
    __hip_bfloat16* Kbf  = (__hip_bfloat16*)(ws + (72l << 20));      // [72, 80)
    __hip_bfloat16* Wkbf = (__hip_bfloat16*)(ws + (80l << 20));      // 512 KiB
    __hip_bfloat16* Wqbf = (__hip_bfloat16*)(ws + (80l << 20) + (512l << 10)); // 384 KiB
    float*          rowsum    = (float*)(ws + (80l << 20) + (896l << 10));     // 64 KiB
    int*            widthFlag = (int*)  (ws + (80l << 20) + (960l << 10));     // 4 B
    __hip_bfloat16* Sb   = (__hip_bfloat16*)(ws + (81l << 20));      // [81, 113)

    constexpr long ZPART = (long)B * T * DH;   // 4,194,304 floats = 16 MiB

    const dim3 blk(256);

    // rowsum accumulates via atomics in the S-pass epilogue.
    hipMemsetAsync(rowsum, 0, (size_t)(B * T) * sizeof(float), stream);

    // w) mask width detection (must precede the fused S epilogue)
    mask_width_kernel<<<dim3(1), blk, 0, stream>>>((const unsigned char*)mask, widthFlag);

    // 0) input prep
    h_prep_kernel<<<dim3(L / 32, DH / 32, B), blk, 0, stream>>>(H, Hbf, Ht, L, DH);
    cvt_f32_bf16_kernel<<<dim3((P * DH) / 1024), blk, 0, stream>>>(Wk, (unsigned short*)Wkbf, (P * DH) / 4);
    cvt_f32_bf16_kernel<<<dim3((P * DG) / 1024), blk, 0, stream>>>(Wq, (unsigned short*)Wqbf, (P * DG) / 4);
    cvt_f32_bf16_kernel<<<dim3((B * T * DG) / 1024), blk, 0, stream>>>(G, (unsigned short*)Gbf, (B * T * DG) / 4);

    // 1) Q = G @ Wq^T   [B*T, P]
    gemm_bt_kernel<__hip_bfloat16, 1, 0><<<dim3((B * T) / 128, P / 128, 1), blk, 0, stream>>>(
        Gbf, Wqbf, Qbf, DG, DG, DG, P, 0, 0, 0, 1.0f,
        nullptr, nullptr, nullptr, 0, 0);
    // 2) K = H @ Wk^T   [B*L, P]   (reads Hbf — last use of [0,32MiB))
    gemm_bt_kernel<__hip_bfloat16, 1, 0><<<dim3((B * L) / 128, P / 128, 1), blk, 0, stream>>>(
        Hbf, Wkbf, Kbf, DH, DH, DH, P, 0, 0, 0, 1.0f,
        nullptr, nullptr, nullptr, 0, 0);
    // 3) P = exp(Q @ K^T * P^-0.5), masked -> 0; rowsum accumulate  [B,T,L]
    gemm_bt_kernel<__hip_bfloat16, 1, 2><<<dim3(T / 128, L / 128, B), blk, 0, stream>>>(
        Qbf, Kbf, Sb, P, P, P, L,
        (long)T * P, (long)L * P, (long)T * L, 0.0625f,
        (const unsigned char*)mask, widthFlag, rowsum, T, 0);
    // 4) Zp[kc] = P @ Ht^T   split-K x2, plain fp32 stores into partials
    gemm_bt_kernel<float, 2, 0><<<dim3(T / 128, DH / 128, B * 2), blk, 0, stream>>>(
        Sb, Ht, Zp, L, L, L, DH,
        (long)T * L, (long)DH * L, (long)T * DH, 1.0f,
        nullptr, nullptr, nullptr, 0, ZPART);
    // 5) Z = (Zp0 + Zp1) / rowsum   streaming combine
    combine_kernel<<<dim3((B * T * DH / 4) / 256), blk, 0, stream>>>(
        Zp, rowsum, Z, ZPART);
}

// Round 5
// 254.552 us; speedup vs baseline: 1.2221x; 1.0247x over previous
//
#include <hip/hip_runtime.h>
#include <hip/hip_bf16.h>

// Problem: B=4, L=4096, DH=1024, T=1024, DG=768, P=256
// Inputs fp32 + bool mask (width auto-detect); OUTPUT fp32.
// Pipeline (softmax FUSED into the GEMMs — no standalone softmax pass):
//   memset rowsum
//   w) mask width probe
//   0) h_prep: H fp32 -> Hbf [B*L,DH] + Ht [B,DH,L]; cvt G,Wk,Wq -> bf16
//      (VECTORIZED: float4 loads, ushort4/short8 16B stores via LDS transpose)
//   1) Qbf = Gbf @ Wqbf^T            [B*T, P]   bf16
//   2) Kbf = Hbf @ Wkbf^T            [B*L, P]   bf16
//   3) P   = exp(Qbf @ Kbf^T / 16) masked->0    [B, T, L] bf16 (UNNORMALIZED)
//      + rowsum[b,t] += sum_l P  (fp32 atomics, from bf16-rounded P)
//   4) Zp[kc] = P @ Ht^T   split-K x2, PLAIN fp32 stores (NO atomics —
//      round-3 ablation: 16.8M epilogue atomicAdds were the Z bottleneck)
//   5) Z = (Zp0 + Zp1) * (1/rowsum[row])  streaming combine, float4
//
// GEMM K-loop: COUNTED-VMCNT pipeline (T4), 3 LDS buffers, prefetch depth 2.
//   s_waitcnt vmcnt(4) -> tile t drained, tile t+1 stays in flight
//   s_barrier; issue tile t+2 into buf[(t+2)%3].
// LDS tiles keep the GRANULE-XOR swizzle (conflicts == 0, verified).
// bf16 EPILOGUES (round 4): routed through the staging LDS (dead after the
// K-loop; vmcnt fully drained, barrier before reuse): ds_write_b16 fragments
// into [128][136] with granule^(row>>3) swizzle, then ds_read_b128 +
// global_store_dwordx4 => 16B/lane coalesced stores (was 64 scalar 2B
// stores/thread at 32B-segment coalescing — G13 violation).
// All GEMMs use XCD-chunked blockIdx swizzle (T1) for per-XCD L2 reuse.

typedef __attribute__((ext_vector_type(8))) short short8;   // 8 bf16 = 4 VGPRs
typedef __attribute__((ext_vector_type(4))) float f32x4;

static __device__ __forceinline__ unsigned short bf16bits(float x) {
    __hip_bfloat16 b = __float2bfloat16(x);
    return *(unsigned short*)&b;
}

// Async global->LDS, 16 B per lane. LDS dest = wave-uniform base + lane*16.
static __device__ __forceinline__ void gload_lds16(const __hip_bfloat16* g,
                                                   __hip_bfloat16* l)
{
    auto gp = (const __attribute__((address_space(1))) unsigned int*)(uintptr_t)g;
    auto lp = (__attribute__((address_space(3))) unsigned int*)(unsigned int)(uintptr_t)l;
    __builtin_amdgcn_global_load_lds(gp, lp, 16, 0, 0);
}

// ---------------------------------------------------------------------------
__global__ __launch_bounds__(256)
void cvt_f32_bf16_kernel(const float* __restrict__ in,
                         unsigned short* __restrict__ out, int n4)
{
    const int i = blockIdx.x * 256 + threadIdx.x;
    if (i >= n4) return;
    float4 v = ((const float4*)in)[i];
    ushort4 o;
    o.x = bf16bits(v.x); o.y = bf16bits(v.y);
    o.z = bf16bits(v.z); o.w = bf16bits(v.w);
    ((ushort4*)out)[i] = o;
}

// ---------------------------------------------------------------------------
// H prep (vectorized): one read of H fp32 -> Hbf (row-major bf16, ushort4
// stores) + Ht (transpose bf16 via LDS, short8 16B stores, 128B segments).
// 64x64 tile per block; LDS [64][72] (144B rows, 16B-aligned).
// ---------------------------------------------------------------------------
__global__ __launch_bounds__(256)
void h_prep_kernel(const float* __restrict__ H,
                   __hip_bfloat16* __restrict__ Hbf,
                   __hip_bfloat16* __restrict__ Ht, int L, int D)
{
    const long b = blockIdx.z;
    const float* Hb = H + b * (long)L * D;
    __hip_bfloat16* Hbfb = Hbf + b * (long)L * D;
    __hip_bfloat16* Htb  = Ht  + b * (long)D * L;
    __shared__ __align__(16) __hip_bfloat16 tile[64][72];  // [d][l], pad 8
    const int l0 = blockIdx.x * 64, d0 = blockIdx.y * 64;
    const int tx = threadIdx.x & 15, ty = threadIdx.x >> 4;  // 16 x 16
    #pragma unroll
    for (int p = 0; p < 4; ++p) {
        const int row = ty + p * 16;     // l index within tile
        const float4 v = *(const float4*)(&Hb[(long)(l0 + row) * D + d0 + tx * 4]);
        ushort4 o;
        o.x = bf16bits(v.x); o.y = bf16bits(v.y);
        o.z = bf16bits(v.z); o.w = bf16bits(v.w);
        *(ushort4*)(&Hbfb[(long)(l0 + row) * D + d0 + tx * 4]) = o;
        tile[tx * 4 + 0][row] = __float2bfloat16(v.x);
        tile[tx * 4 + 1][row] = __float2bfloat16(v.y);
        tile[tx * 4 + 2][row] = __float2bfloat16(v.z);
        tile[tx * 4 + 3][row] = __float2bfloat16(v.w);
    }
    __syncthreads();
    const int ll = threadIdx.x & 7;      // 8 threads x 16B = 128B per d-row
    const int dq = threadIdx.x >> 3;     // 32 d-rows per pass
    #pragma unroll
    for (int q = 0; q < 2; ++q) {
        const int dd = dq + q * 32;
        const short8 v = *(const short8*)(&tile[dd][ll * 8]);
        *(short8*)(&Htb[(long)(d0 + dd) * L + l0 + ll * 8]) = v;
    }
}

// ---------------------------------------------------------------------------
// GEMM: C[M,N] (op)= scale * A[M,K] @ Bm[N,K]^T  (bf16 row-major, K contig)
// 128x128 tile, 4 waves, wave 64x64 via 4x4 MFMA 16x16x32 bf16.
// Counted-vmcnt 3-buffer pipeline; LDS pool reused for the bf16 epilogue.
// MODE 0: plain store, scaled. OutT bf16 -> LDS-staged vectorized writeout;
//         OutT f32 (Z partials, SPLITK>1) -> direct stores at kc*partStride.
// MODE 2: P = exp(scale*acc), masked cols -> 0; bf16 via LDS writeout;
//         accumulate fp32 row-sums (from the bf16-ROUNDED values).
// ---------------------------------------------------------------------------
template <typename OutT, int SPLITK, int MODE>
__global__ __launch_bounds__(256)
void gemm_bt_kernel(const __hip_bfloat16* __restrict__ A,
                    const __hip_bfloat16* __restrict__ Bm,
                    OutT* __restrict__ C,
                    int K, int lda, int ldb, int ldc,
                    long batchStrideA, long batchStrideB, long batchStrideC,
                    float scale,
                    const unsigned char* __restrict__ mask,
                    const int* __restrict__ widthPtr,
                    float* __restrict__ rowsum,
                    int rowsumStride,
                    long partStride)
{
    // XCD-chunked swizzle (T1).
    int bx = blockIdx.x, by = blockIdx.y, bz = blockIdx.z;
    {
        const int nwg = gridDim.x * gridDim.y * gridDim.z;
        if ((nwg & 7) == 0) {
            int lin = bx + gridDim.x * (by + gridDim.y * bz);
            lin = (lin & 7) * (nwg >> 3) + (lin >> 3);
            bx = lin % gridDim.x;
            const int t = lin / gridDim.x;
            by = t % gridDim.y;
            bz = t / gridDim.y;
        }
    }

    const int zb = bz / SPLITK;
    const int kc = bz % SPLITK;
    A  += (long)zb * batchStrideA;
    Bm += (long)zb * batchStrideB;
    C  += (long)zb * batchStrideC + (long)kc * partStride;
    const int Kloc  = K / SPLITK;
    const int kbase = kc * Kloc;
    const int NT    = Kloc / 32;          // k-tiles

    const int tid  = threadIdx.x;
    const int lane = tid & 63;
    const int wave = tid >> 6;
    const int wm = (wave & 1) * 64;
    const int wn = (wave >> 1) * 64;
    const int rowBase = bx * 128;
    const int colBase = by * 128;

    // 48 KiB pool: As[3][128][32] + Bs[3][128][32] during K-loop;
    // reused as bf16 C-stage [128][136] in the epilogue.
    __shared__ __align__(16) __hip_bfloat16 lds_pool[24576];
    __hip_bfloat16* AsP = lds_pool;            // buf*4096 + row*32 + col
    __hip_bfloat16* BsP = lds_pool + 12288;

    f32x4 acc[4][4];
    #pragma unroll
    for (int i = 0; i < 4; ++i)
        #pragma unroll
        for (int j = 0; j < 4; ++j)
            acc[i][j] = (f32x4){0.f, 0.f, 0.f, 0.f};

    // Staging: wave w covers rows [w*32, w*32+32) as two 16-row x 1024 B chunks.
    // Lane i: LDS lands at (row = i>>2, granule g = i&3). Pre-swizzle the
    // GLOBAL source granule: q = g ^ ((row>>1)&3)  (involution per row).
    const int srow = lane >> 2;
    const int scol = ((lane & 3) ^ ((lane >> 3) & 3)) * 8;   // swizzled source col
    const long ar0 = (long)(rowBase + wave * 32 + srow) * lda;
    const long ar1 = ar0 + 16l * lda;
    const long br0 = (long)(colBase + wave * 32 + srow) * ldb;
    const long br1 = br0 + 16l * ldb;

    const int mrow = lane & 15;         // fragment m/n index
    // Swizzled fragment k-offset (row bases ≡0 mod 16 -> lane-only term).
    const int koff = (((lane >> 4) ^ ((lane >> 1) & 3)) * 8);

    // Per wave each tile issues EXACTLY 4 global_load_lds ops (vmcnt units).
    auto stage = [&](int buf, int t) {
        const int kk = kbase + t * 32 + scol;
        gload_lds16(A  + ar0 + kk, AsP + buf * 4096 + wave * 1024);
        gload_lds16(A  + ar1 + kk, AsP + buf * 4096 + wave * 1024 + 512);
        gload_lds16(Bm + br0 + kk, BsP + buf * 4096 + wave * 1024);
        gload_lds16(Bm + br1 + kk, BsP + buf * 4096 + wave * 1024 + 512);
    };

    // Prologue: tiles 0,1 in flight (8 vmcnt ops/wave). No barrier yet.
    stage(0, 0);
    if (NT > 1) stage(1, 1);

    int cur = 0;
    for (int t = 0; t < NT; ++t) {
        // Drain OWN tile-t loads only; tile t+1 stays in flight across the
        // barrier (counted vmcnt — never drain to 0 in the main loop).
        if (t + 1 < NT)
            asm volatile("s_waitcnt vmcnt(4)" ::: "memory");
        else
            asm volatile("s_waitcnt vmcnt(0)" ::: "memory");
        __builtin_amdgcn_s_barrier();
        if (t + 2 < NT) {
            const int nxt2 = (cur >= 1) ? cur - 1 : cur + 2;   // (cur+2)%3
            stage(nxt2, t + 2);
        }

        short8 af[4], bf[4];
        #pragma unroll
        for (int mi = 0; mi < 4; ++mi)
            af[mi] = *(const short8*)(AsP + cur * 4096 + (wm + mi * 16 + mrow) * 32 + koff);
        #pragma unroll
        for (int ni = 0; ni < 4; ++ni)
            bf[ni] = *(const short8*)(BsP + cur * 4096 + (wn + ni * 16 + mrow) * 32 + koff);

        #pragma unroll
        for (int mi = 0; mi < 4; ++mi)
            #pragma unroll
            for (int ni = 0; ni < 4; ++ni)
                acc[mi][ni] = __builtin_amdgcn_mfma_f32_16x16x32_bf16(
                    af[mi], bf[ni], acc[mi][ni], 0, 0, 0);
        cur = (cur == 2) ? 0 : cur + 1;
    }

    // C/D layout (verified m89/m91): col = lane&15, row = (lane>>4)*4 + r
    const int crow0 = (lane >> 4) * 4;
    const int ccol  = lane & 15;

    if constexpr (MODE == 2 || sizeof(OutT) == 2) {
        // --- bf16 LDS-staged vectorized writeout ---
        // Pool is safe to reuse: last-iter vmcnt(0) drained all gload_lds,
        // and this barrier closes the final ds_reads.
        __syncthreads();
        __hip_bfloat16* cst = lds_pool;    // [128][136], granule^(row>>3)

        if constexpr (MODE == 2) {
            const int w = *widthPtr;
            const long mbase = (long)zb * ldc;   // mask row length == ldc == L
            bool mk[4];
            #pragma unroll
            for (int ni = 0; ni < 4; ++ni) {
                const long midx = mbase + colBase + wn + ni * 16 + ccol;
                if (w == 1)      mk[ni] = mask[midx] != 0;
                else if (w == 2) mk[ni] = ((const unsigned short*)mask)[midx] != 0;
                else if (w == 4) mk[ni] = ((const unsigned int*)mask)[midx] != 0;
                else { uint2 q = ((const uint2*)mask)[midx]; mk[ni] = (q.x | q.y) != 0; }
            }
            #pragma unroll
            for (int mi = 0; mi < 4; ++mi) {
                #pragma unroll
                for (int r = 0; r < 4; ++r) {
                    const int row = wm + mi * 16 + crow0 + r;
                    float rs = 0.f;
                    #pragma unroll
                    for (int ni = 0; ni < 4; ++ni) {
                        const int col = wn + ni * 16 + ccol;
                        const float e = mk[ni] ? 0.f
                                               : __expf(acc[mi][ni][r] * scale);
                        const __hip_bfloat16 pb = __float2bfloat16(e);
                        cst[row * 136 + (((col >> 3) ^ (row >> 3)) << 3) + (col & 7)] = pb;
                        rs += __bfloat162float(pb);
                    }
                    rs += __shfl_xor(rs, 1, 64);
                    rs += __shfl_xor(rs, 2, 64);
                    rs += __shfl_xor(rs, 4, 64);
                    rs += __shfl_xor(rs, 8, 64);
                    if ((lane & 15) == 0)
                        atomicAdd(&rowsum[(long)zb * rowsumStride + rowBase + row], rs);
                }
            }
        } else {
            #pragma unroll
            for (int mi = 0; mi < 4; ++mi) {
                #pragma unroll
                for (int ni = 0; ni < 4; ++ni) {
                    #pragma unroll
                    for (int r = 0; r < 4; ++r) {
                        const int row = wm + mi * 16 + crow0 + r;
                        const int col = wn + ni * 16 + ccol;
                        cst[row * 136 + (((col >> 3) ^ (row >> 3)) << 3) + (col & 7)] =
                            __float2bfloat16(acc[mi][ni][r] * scale);
                    }
                }
            }
        }
        __syncthreads();
        // 8x (ds_read_b128 + global_store_dwordx4): 16 lanes x 16B = 256B
        // contiguous per row; granule^(row>>3) gives 8 lanes/bank-quad (optimal).
        const int g   = tid & 15;
        const int r4  = tid >> 4;                 // == row>>3 for all k
        const int lof = ((g ^ r4) << 3);
        #pragma unroll
        for (int k = 0; k < 8; ++k) {
            const int row = r4 * 8 + k;
            const short8 v = *(const short8*)(cst + row * 136 + lof);
            *(short8*)(&((__hip_bfloat16*)C)[(long)(rowBase + row) * ldc + colBase + g * 8]) = v;
        }
    } else {
        // fp32 direct stores (Z partials)
        #pragma unroll
        for (int mi = 0; mi < 4; ++mi) {
            #pragma unroll
            for (int ni = 0; ni < 4; ++ni) {
                #pragma unroll
                for (int r = 0; r < 4; ++r) {
                    const int row = rowBase + wm + mi * 16 + crow0 + r;
                    const int col = colBase + wn + ni * 16 + ccol;
                    ((float*)C)[(long)row * ldc + col] = acc[mi][ni][r] * scale;
                }
            }
        }
    }
}

// ---------------------------------------------------------------------------
// Combine: Z = (Zp0 + Zp1) * (1/rowsum[row]).  Streaming, float4.
// ---------------------------------------------------------------------------
__global__ __launch_bounds__(256)
void combine_kernel(const float* __restrict__ Zp,
                    const float* __restrict__ rowsum,
                    float* __restrict__ Z, long partStride)
{
    const int i = blockIdx.x * 256 + threadIdx.x;   // float4 index
    const float4 a = ((const float4*)Zp)[i];
    const float4 b = ((const float4*)(Zp + partStride))[i];
    const float inv = 1.0f / rowsum[i >> 8];        // (4*i)/1024
    float4 o;
    o.x = (a.x + b.x) * inv;
    o.y = (a.y + b.y) * inv;
    o.z = (a.z + b.z) * inv;
    o.w = (a.w + b.w) * inv;
    ((float4*)Z)[i] = o;
}

// ---------------------------------------------------------------------------
// Mask element-width detector (16384 bools, ~50% True).
// ---------------------------------------------------------------------------
__global__ __launch_bounds__(256)
void mask_width_kernel(const unsigned char* __restrict__ m, int* __restrict__ widthOut)
{
    __shared__ int c1, c2, c4, c8, cp;
    if (threadIdx.x == 0) { c1 = c2 = c4 = c8 = cp = 0; }
    __syncthreads();
    int l1 = 0, l2 = 0, l4 = 0, l8 = 0, lp = 0;
    const unsigned short* m16 = (const unsigned short*)m;
    const unsigned int*   m32 = (const unsigned int*)m;
    for (int i = threadIdx.x; i < 16384; i += 256) l1 += (m[i] != 0);
    for (int i = threadIdx.x; i < 8192;  i += 256) {
        l2 += (m16[i] != 0);
        lp += ((m[2 * i] != 0) == (m[2 * i + 1] != 0));
    }
    for (int i = threadIdx.x; i < 4096;  i += 256) l4 += (m32[i] != 0);
    for (int i = threadIdx.x; i < 2048;  i += 256) l8 += ((m32[2 * i] | m32[2 * i + 1]) != 0);
    atomicAdd(&c1, l1); atomicAdd(&c2, l2); atomicAdd(&c4, l4);
    atomicAdd(&c8, l8); atomicAdd(&cp, lp);
    __syncthreads();
    if (threadIdx.x == 0) {
        const float f1 = fabsf(c1 / 16384.f - 0.5f);
        const float f2 = fabsf(c2 / 8192.f  - 0.5f);
        const float f4 = fabsf(c4 / 4096.f  - 0.5f);
        const float f8 = fabsf(c8 / 2048.f  - 0.5f);
        int w = 1; float best = f1;
        if (f2 < best) { best = f2; w = 2; }
        if (f4 < best) { best = f4; w = 4; }
        if (f8 < best) { best = f8; w = 8; }
        if (w == 1 && cp > 7400) w = 2;
        *widthOut = w;
    }
}

// ---------------------------------------------------------------------------
extern "C" void kernel_launch(void* const* d_in, const int* in_sizes, int n_in,
                              void* d_out, int out_size, void* d_ws, size_t ws_size,
                              hipStream_t stream)
{
    constexpr int B = 4, L = 4096, DH = 1024, T = 1024, DG = 768, P = 256;

    const float* H  = (const float*)d_in[0];
    const float* G  = (const float*)d_in[1];
    const void*  mask = d_in[2];
    const float* Wk = (const float*)d_in[3];
    const float* Wq = (const float*)d_in[4];
    for (int i = 0; i < n_in; ++i) {
        switch (in_sizes[i]) {
            case B * L * DH: H    = (const float*)d_in[i]; break;
            case B * T * DG: G    = (const float*)d_in[i]; break;
            case B * L:      mask = d_in[i];               break;
            case P * DH:     Wk   = (const float*)d_in[i]; break;
            case P * DG:     Wq   = (const float*)d_in[i]; break;
        }
    }
    float* Z = (float*)d_out;

    char* ws = (char*)d_ws;
    __hip_bfloat16* Hbf  = (__hip_bfloat16*)ws;                      // [0, 32 MiB) — dead after K-GEMM
    float*          Zp   = (float*)ws;                               // [0, 32 MiB): Zp0+Zp1 (over dead Hbf)
    __hip_bfloat16* Ht   = (__hip_bfloat16*)(ws + (32l << 20));      // [32, 64)
    __hip_bfloat16* Gbf  = (__hip_bfloat16*)(ws + (64l << 20));      // [64, 70)
    __hip_bfloat16* Qbf  = (__hip_bfloat16*)(ws + (70l << 20));      // [70, 72)
    __hip_bfloat16* Kbf  = (__hip_bfloat16*)(ws + (72l << 20));      // [72, 80)
    __hip_bfloat16* Wkbf = (__hip_bfloat16*)(ws + (80l << 20));      // 512 KiB
    __hip_bfloat16* Wqbf = (__hip_bfloat16*)(ws + (80l << 20) + (512l << 10)); // 384 KiB
    float*          rowsum    = (float*)(ws + (80l << 20) + (896l << 10));     // 64 KiB
    int*            widthFlag = (int*)  (ws + (80l << 20) + (960l << 10));     // 4 B
    __hip_bfloat16* Sb   = (__hip_bfloat16*)(ws + (81l << 20));      // [81, 113)

    constexpr long ZPART = (long)B * T * DH;   // 4,194,304 floats = 16 MiB

    const dim3 blk(256);

    // rowsum accumulates via atomics in the S-pass epilogue.
    hipMemsetAsync(rowsum, 0, (size_t)(B * T) * sizeof(float), stream);

    // w) mask width detection (must precede the fused S epilogue)
    mask_width_kernel<<<dim3(1), blk, 0, stream>>>((const unsigned char*)mask, widthFlag);

    // 0) input prep
    h_prep_kernel<<<dim3(L / 64, DH / 64, B), blk, 0, stream>>>(H, Hbf, Ht, L, DH);
    cvt_f32_bf16_kernel<<<dim3((P * DH) / 1024), blk, 0, stream>>>(Wk, (unsigned short*)Wkbf, (P * DH) / 4);
    cvt_f32_bf16_kernel<<<dim3((P * DG) / 1024), blk, 0, stream>>>(Wq, (unsigned short*)Wqbf, (P * DG) / 4);
    cvt_f32_bf16_kernel<<<dim3((B * T * DG) / 1024), blk, 0, stream>>>(G, (unsigned short*)Gbf, (B * T * DG) / 4);

    // 1) Q = G @ Wq^T   [B*T, P]
    gemm_bt_kernel<__hip_bfloat16, 1, 0><<<dim3((B * T) / 128, P / 128, 1), blk, 0, stream>>>(
        Gbf, Wqbf, Qbf, DG, DG, DG, P, 0, 0, 0, 1.0f,
        nullptr, nullptr, nullptr, 0, 0);
    // 2) K = H @ Wk^T   [B*L, P]   (reads Hbf — last use of [0,32MiB))
    gemm_bt_kernel<__hip_bfloat16, 1, 0><<<dim3((B * L) / 128, P / 128, 1), blk, 0, stream>>>(
        Hbf, Wkbf, Kbf, DH, DH, DH, P, 0, 0, 0, 1.0f,
        nullptr, nullptr, nullptr, 0, 0);
    // 3) P = exp(Q @ K^T * P^-0.5), masked -> 0; rowsum accumulate  [B,T,L]
    gemm_bt_kernel<__hip_bfloat16, 1, 2><<<dim3(T / 128, L / 128, B), blk, 0, stream>>>(
        Qbf, Kbf, Sb, P, P, P, L,
        (long)T * P, (long)L * P, (long)T * L, 0.0625f,
        (const unsigned char*)mask, widthFlag, rowsum, T, 0);
    // 4) Zp[kc] = P @ Ht^T   split-K x2, plain fp32 stores into partials
    gemm_bt_kernel<float, 2, 0><<<dim3(T / 128, DH / 128, B * 2), blk, 0, stream>>>(
        Sb, Ht, Zp, L, L, L, DH,
        (long)T * L, (long)DH * L, (long)T * DH, 1.0f,
        nullptr, nullptr, nullptr, 0, ZPART);
    // 5) Z = (Zp0 + Zp1) / rowsum   streaming combine
    combine_kernel<<<dim3((B * T * DH / 4) / 256), blk, 0, stream>>>(
        Zp, rowsum, Z, ZPART);
}

// Round 6
// 239.761 us; speedup vs baseline: 1.2975x; 1.0617x over previous
//
#include <hip/hip_runtime.h>
#include <hip/hip_bf16.h>

// Problem: B=4, L=4096, DH=1024, T=1024, DG=768, P=256
// Inputs fp32 + bool mask (width auto-detect); OUTPUT fp32.
//
// MASK COMPACTION (round 6): ~50% of l are masked; masked columns have
// alpha == 0 exactly, so ALL downstream work on them is dead. A prefix-scan
// builds per batch the ordered valid-l list idx[b][c] (c < Lc[b]) and
// Lc_pad = round_up(Lc, 128). Every pass then works in COMPACT index space:
//   scan)  idx, Lc, Lc_pad from mask
//   0) h_prep GATHERS valid H rows -> Hbf_c [compact rows] + Ht_c [compact
//      cols]; pad rows/cols [Lc, Lc_pad) zeroed. Reads/writes HALVE.
//   1) Qbf = Gbf @ Wqbf^T                       [B*T, P]   (unchanged)
//   2) K_c = Hbf_c @ Wkbf^T  row-tiles >= Lc_pad exit      [B*L cap, P]
//   3) P_c = exp(Qbf @ K_c^T / 16)   col-tiles >= Lc_pad exit; cols >= Lc
//      zeroed by an index COMPARE (no mask loads); rowsum fp32 atomics
//   4) Zp[kc] = P_c @ Ht_c^T   runtime K = Lc_pad[b] (HALF the MFMAs),
//      split-K x2, plain fp32 stores
//   5) Z = (Zp0 + Zp1) * (1/rowsum[row])  streaming combine
// Valid-column P values are bit-identical to the uncompacted version.
//
// GEMM K-loop: COUNTED-VMCNT pipeline (T4), 3 LDS buffers, prefetch depth 2;
// GRANULE-XOR LDS swizzle (conflicts == 0, verified); bf16 epilogues via
// LDS-staged 16B/lane vectorized writeout; XCD-chunked blockIdx swizzle (T1).
// Z epilogue: plain stores (round-3 ablation: epilogue atomics were the
// bottleneck); split-K 2 (measured best).

typedef __attribute__((ext_vector_type(8))) short short8;   // 8 bf16 = 4 VGPRs
typedef __attribute__((ext_vector_type(4))) float f32x4;

static __device__ __forceinline__ unsigned short bf16bits(float x) {
    __hip_bfloat16 b = __float2bfloat16(x);
    return *(unsigned short*)&b;
}

// Async global->LDS, 16 B per lane. LDS dest = wave-uniform base + lane*16.
static __device__ __forceinline__ void gload_lds16(const __hip_bfloat16* g,
                                                   __hip_bfloat16* l)
{
    auto gp = (const __attribute__((address_space(1))) unsigned int*)(uintptr_t)g;
    auto lp = (__attribute__((address_space(3))) unsigned int*)(unsigned int)(uintptr_t)l;
    __builtin_amdgcn_global_load_lds(gp, lp, 16, 0, 0);
}

// ---------------------------------------------------------------------------
__global__ __launch_bounds__(256)
void cvt_f32_bf16_kernel(const float* __restrict__ in,
                         unsigned short* __restrict__ out, int n4)
{
    const int i = blockIdx.x * 256 + threadIdx.x;
    if (i >= n4) return;
    float4 v = ((const float4*)in)[i];
    ushort4 o;
    o.x = bf16bits(v.x); o.y = bf16bits(v.y);
    o.z = bf16bits(v.z); o.w = bf16bits(v.w);
    ((ushort4*)out)[i] = o;
}

// ---------------------------------------------------------------------------
// Mask element-width detector (16384 bools, ~50% True).
// ---------------------------------------------------------------------------
__global__ __launch_bounds__(256)
void mask_width_kernel(const unsigned char* __restrict__ m, int* __restrict__ widthOut)
{
    __shared__ int c1, c2, c4, c8, cp;
    if (threadIdx.x == 0) { c1 = c2 = c4 = c8 = cp = 0; }
    __syncthreads();
    int l1 = 0, l2 = 0, l4 = 0, l8 = 0, lp = 0;
    const unsigned short* m16 = (const unsigned short*)m;
    const unsigned int*   m32 = (const unsigned int*)m;
    for (int i = threadIdx.x; i < 16384; i += 256) l1 += (m[i] != 0);
    for (int i = threadIdx.x; i < 8192;  i += 256) {
        l2 += (m16[i] != 0);
        lp += ((m[2 * i] != 0) == (m[2 * i + 1] != 0));
    }
    for (int i = threadIdx.x; i < 4096;  i += 256) l4 += (m32[i] != 0);
    for (int i = threadIdx.x; i < 2048;  i += 256) l8 += ((m32[2 * i] | m32[2 * i + 1]) != 0);
    atomicAdd(&c1, l1); atomicAdd(&c2, l2); atomicAdd(&c4, l4);
    atomicAdd(&c8, l8); atomicAdd(&cp, lp);
    __syncthreads();
    if (threadIdx.x == 0) {
        const float f1 = fabsf(c1 / 16384.f - 0.5f);
        const float f2 = fabsf(c2 / 8192.f  - 0.5f);
        const float f4 = fabsf(c4 / 4096.f  - 0.5f);
        const float f8 = fabsf(c8 / 2048.f  - 0.5f);
        int w = 1; float best = f1;
        if (f2 < best) { best = f2; w = 2; }
        if (f4 < best) { best = f4; w = 4; }
        if (f8 < best) { best = f8; w = 8; }
        if (w == 1 && cp > 7400) w = 2;
        *widthOut = w;
    }
}

// ---------------------------------------------------------------------------
// Valid-l compaction scan. One block per batch; 4096 l's, 16 per thread.
// idx[b][c] = l of c-th valid key; lc[b] = #valid; lcpad[b] = ceil128(lc).
// ---------------------------------------------------------------------------
__global__ __launch_bounds__(256)
void mask_scan_kernel(const void* __restrict__ mask, const int* __restrict__ widthPtr,
                      unsigned short* __restrict__ idx,
                      int* __restrict__ lc, int* __restrict__ lcpad, int L)
{
    const int b = blockIdx.x;
    const int tid = threadIdx.x;
    const int w = *widthPtr;
    const unsigned char*  m8  = (const unsigned char*)mask;
    const unsigned short* m16 = (const unsigned short*)mask;
    const unsigned int*   m32 = (const unsigned int*)mask;
    const uint2*          m64 = (const uint2*)mask;

    bool v[16];
    int cnt = 0;
    #pragma unroll
    for (int i = 0; i < 16; ++i) {
        const int l = tid * 16 + i;
        const long mi = (long)b * L + l;
        bool masked;
        if (w == 1)      masked = m8[mi] != 0;
        else if (w == 2) masked = m16[mi] != 0;
        else if (w == 4) masked = m32[mi] != 0;
        else             { uint2 q = m64[mi]; masked = (q.x | q.y) != 0; }
        v[i] = !masked;
        cnt += v[i] ? 1 : 0;
    }
    // inclusive scan within wave, then wave offsets via LDS
    __shared__ int waveTot[4];
    int pre = cnt;
    #pragma unroll
    for (int off = 1; off < 64; off <<= 1) {
        const int t = __shfl_up(pre, off, 64);
        if ((tid & 63) >= off) pre += t;
    }
    if ((tid & 63) == 63) waveTot[tid >> 6] = pre;
    __syncthreads();
    int waveOff = 0;
    for (int wv = 0; wv < (tid >> 6); ++wv) waveOff += waveTot[wv];
    int o = waveOff + pre - cnt;          // exclusive prefix for this thread
    #pragma unroll
    for (int i = 0; i < 16; ++i)
        if (v[i]) idx[(long)b * L + (o++)] = (unsigned short)(tid * 16 + i);
    if (tid == 255) {
        const int total = waveOff + pre;
        lc[b] = total;
        lcpad[b] = (total + 127) & ~127;
    }
}

// ---------------------------------------------------------------------------
// H prep with row GATHER: compact row c <- H row idx[b][c] (fp32, coalesced
// 256B segments) -> Hbf_c (compact rows, ushort4) + Ht_c (compact cols,
// short8 via LDS transpose). Pad rows/cols [Lc, Lc_pad) written as ZERO.
// ---------------------------------------------------------------------------
__global__ __launch_bounds__(256)
void h_prep_kernel(const float* __restrict__ H,
                   __hip_bfloat16* __restrict__ Hbf,
                   __hip_bfloat16* __restrict__ Ht,
                   const unsigned short* __restrict__ idx,
                   const int* __restrict__ lc, const int* __restrict__ lcpad,
                   int L, int D)
{
    const int b = blockIdx.z;
    const int c0 = blockIdx.x * 64;
    if (c0 >= lcpad[b]) return;           // uniform: beyond padded extent
    const int Lcb = lc[b];
    const float* Hb = H + (long)b * L * D;
    __hip_bfloat16* Hbfb = Hbf + (long)b * L * D;
    __hip_bfloat16* Htb  = Ht  + (long)b * D * L;
    __shared__ __align__(16) __hip_bfloat16 tile[64][72];  // [d][c], pad 8
    const int d0 = blockIdx.y * 64;
    const int tx = threadIdx.x & 15, ty = threadIdx.x >> 4;  // 16 x 16
    #pragma unroll
    for (int p = 0; p < 4; ++p) {
        const int row = ty + p * 16;     // compact index within tile
        const int c = c0 + row;
        float4 v = {0.f, 0.f, 0.f, 0.f};
        if (c < Lcb) {
            const int l = idx[(long)b * L + c];
            v = *(const float4*)(&Hb[(long)l * D + d0 + tx * 4]);
        }
        ushort4 o;
        o.x = bf16bits(v.x); o.y = bf16bits(v.y);
        o.z = bf16bits(v.z); o.w = bf16bits(v.w);
        *(ushort4*)(&Hbfb[(long)c * D + d0 + tx * 4]) = o;
        tile[tx * 4 + 0][row] = __float2bfloat16(v.x);
        tile[tx * 4 + 1][row] = __float2bfloat16(v.y);
        tile[tx * 4 + 2][row] = __float2bfloat16(v.z);
        tile[tx * 4 + 3][row] = __float2bfloat16(v.w);
    }
    __syncthreads();
    const int ll = threadIdx.x & 7;      // 8 threads x 16B = 128B per d-row
    const int dq = threadIdx.x >> 3;     // 32 d-rows per pass
    #pragma unroll
    for (int q = 0; q < 2; ++q) {
        const int dd = dq + q * 32;
        const short8 v = *(const short8*)(&tile[dd][ll * 8]);
        *(short8*)(&Htb[(long)(d0 + dd) * L + c0 + ll * 8]) = v;
    }
}

// ---------------------------------------------------------------------------
// GEMM: C[M,N] (op)= scale * A[M,K] @ Bm[N,K]^T  (bf16 row-major, K contig)
// 128x128 tile, 4 waves, wave 64x64 via 4x4 MFMA 16x16x32 bf16.
// Counted-vmcnt 3-buffer pipeline; LDS pool reused for the bf16 epilogue.
// MODE 0: plain store. bf16 -> LDS-staged vectorized writeout; f32 ->
//         direct stores at kc*partStride (Z partials).
// MODE 2: P = exp(scale*acc); cols >= lc[zb] -> 0 (compare, no mask loads);
//         bf16 via LDS writeout; fp32 row-sum atomics (bf16-rounded values).
// CMODE 0: none. 1: row-limit exit (rows rowBase%Lfull >= lcpad[b]).
//         2: col-limit exit (colBase >= lcpad[zb]). 3: runtime K = lcpad[zb].
// ---------------------------------------------------------------------------
template <typename OutT, int SPLITK, int MODE, int CMODE>
__global__ __launch_bounds__(256)
void gemm_bt_kernel(const __hip_bfloat16* __restrict__ A,
                    const __hip_bfloat16* __restrict__ Bm,
                    OutT* __restrict__ C,
                    int K, int lda, int ldb, int ldc,
                    long batchStrideA, long batchStrideB, long batchStrideC,
                    float scale,
                    float* __restrict__ rowsum,
                    int rowsumStride,
                    long partStride,
                    const int* __restrict__ lc,
                    const int* __restrict__ lcpad,
                    int Lfull)
{
    // XCD-chunked swizzle (T1).
    int bx = blockIdx.x, by = blockIdx.y, bz = blockIdx.z;
    {
        const int nwg = gridDim.x * gridDim.y * gridDim.z;
        if ((nwg & 7) == 0) {
            int lin = bx + gridDim.x * (by + gridDim.y * bz);
            lin = (lin & 7) * (nwg >> 3) + (lin >> 3);
            bx = lin % gridDim.x;
            const int t = lin / gridDim.x;
            by = t % gridDim.y;
            bz = t / gridDim.y;
        }
    }

    const int zb = bz / SPLITK;
    const int kc = bz % SPLITK;
    const int rowBase = bx * 128;
    const int colBase = by * 128;

    if constexpr (CMODE == 1) {          // K-GEMM: skip masked-out row tiles
        const int bb = rowBase / Lfull;
        if (rowBase - bb * Lfull >= lcpad[bb]) return;
    }
    if constexpr (CMODE == 2) {          // S-GEMM: skip masked-out col tiles
        if (colBase >= lcpad[zb]) return;
    }

    A  += (long)zb * batchStrideA;
    Bm += (long)zb * batchStrideB;
    C  += (long)zb * batchStrideC + (long)kc * partStride;
    int Kdyn = K;
    if constexpr (CMODE == 3) Kdyn = lcpad[zb];   // Z-GEMM: compacted K
    const int Kloc  = Kdyn / SPLITK;
    const int kbase = kc * Kloc;
    const int NT    = Kloc / 32;          // k-tiles (>= 2: lcpad >= 128)

    const int tid  = threadIdx.x;
    const int lane = tid & 63;
    const int wave = tid >> 6;
    const int wm = (wave & 1) * 64;
    const int wn = (wave >> 1) * 64;

    // 48 KiB pool: As[3][128][32] + Bs[3][128][32] during K-loop;
    // reused as bf16 C-stage [128][136] in the epilogue.
    __shared__ __align__(16) __hip_bfloat16 lds_pool[24576];
    __hip_bfloat16* AsP = lds_pool;            // buf*4096 + row*32 + col
    __hip_bfloat16* BsP = lds_pool + 12288;

    f32x4 acc[4][4];
    #pragma unroll
    for (int i = 0; i < 4; ++i)
        #pragma unroll
        for (int j = 0; j < 4; ++j)
            acc[i][j] = (f32x4){0.f, 0.f, 0.f, 0.f};

    // Staging: wave w covers rows [w*32, w*32+32) as two 16-row x 1024 B chunks.
    // Lane i: LDS lands at (row = i>>2, granule g = i&3). Pre-swizzle the
    // GLOBAL source granule: q = g ^ ((row>>1)&3)  (involution per row).
    const int srow = lane >> 2;
    const int scol = ((lane & 3) ^ ((lane >> 3) & 3)) * 8;   // swizzled source col
    const long ar0 = (long)(rowBase + wave * 32 + srow) * lda;
    const long ar1 = ar0 + 16l * lda;
    const long br0 = (long)(colBase + wave * 32 + srow) * ldb;
    const long br1 = br0 + 16l * ldb;

    const int mrow = lane & 15;         // fragment m/n index
    // Swizzled fragment k-offset (row bases ≡0 mod 16 -> lane-only term).
    const int koff = (((lane >> 4) ^ ((lane >> 1) & 3)) * 8);

    // Per wave each tile issues EXACTLY 4 global_load_lds ops (vmcnt units).
    auto stage = [&](int buf, int t) {
        const int kk = kbase + t * 32 + scol;
        gload_lds16(A  + ar0 + kk, AsP + buf * 4096 + wave * 1024);
        gload_lds16(A  + ar1 + kk, AsP + buf * 4096 + wave * 1024 + 512);
        gload_lds16(Bm + br0 + kk, BsP + buf * 4096 + wave * 1024);
        gload_lds16(Bm + br1 + kk, BsP + buf * 4096 + wave * 1024 + 512);
    };

    // Prologue: tiles 0,1 in flight (8 vmcnt ops/wave). No barrier yet.
    stage(0, 0);
    if (NT > 1) stage(1, 1);

    int cur = 0;
    for (int t = 0; t < NT; ++t) {
        // Drain OWN tile-t loads only; tile t+1 stays in flight across the
        // barrier (counted vmcnt — never drain to 0 in the main loop).
        if (t + 1 < NT)
            asm volatile("s_waitcnt vmcnt(4)" ::: "memory");
        else
            asm volatile("s_waitcnt vmcnt(0)" ::: "memory");
        __builtin_amdgcn_s_barrier();
        if (t + 2 < NT) {
            const int nxt2 = (cur >= 1) ? cur - 1 : cur + 2;   // (cur+2)%3
            stage(nxt2, t + 2);
        }

        short8 af[4], bf[4];
        #pragma unroll
        for (int mi = 0; mi < 4; ++mi)
            af[mi] = *(const short8*)(AsP + cur * 4096 + (wm + mi * 16 + mrow) * 32 + koff);
        #pragma unroll
        for (int ni = 0; ni < 4; ++ni)
            bf[ni] = *(const short8*)(BsP + cur * 4096 + (wn + ni * 16 + mrow) * 32 + koff);

        #pragma unroll
        for (int mi = 0; mi < 4; ++mi)
            #pragma unroll
            for (int ni = 0; ni < 4; ++ni)
                acc[mi][ni] = __builtin_amdgcn_mfma_f32_16x16x32_bf16(
                    af[mi], bf[ni], acc[mi][ni], 0, 0, 0);
        cur = (cur == 2) ? 0 : cur + 1;
    }

    // C/D layout (verified m89/m91): col = lane&15, row = (lane>>4)*4 + r
    const int crow0 = (lane >> 4) * 4;
    const int ccol  = lane & 15;

    if constexpr (MODE == 2 || sizeof(OutT) == 2) {
        // --- bf16 LDS-staged vectorized writeout ---
        __syncthreads();                   // pool safe: vmcnt(0) drained above
        __hip_bfloat16* cst = lds_pool;    // [128][136], granule^(row>>3)

        if constexpr (MODE == 2) {
            const int lcv = lc[zb];        // valid-col limit (compare, no loads)
            bool mk[4];
            #pragma unroll
            for (int ni = 0; ni < 4; ++ni)
                mk[ni] = (colBase + wn + ni * 16 + ccol) >= lcv;
            #pragma unroll
            for (int mi = 0; mi < 4; ++mi) {
                #pragma unroll
                for (int r = 0; r < 4; ++r) {
                    const int row = wm + mi * 16 + crow0 + r;
                    float rs = 0.f;
                    #pragma unroll
                    for (int ni = 0; ni < 4; ++ni) {
                        const int col = wn + ni * 16 + ccol;
                        const float e = mk[ni] ? 0.f
                                               : __expf(acc[mi][ni][r] * scale);
                        const __hip_bfloat16 pb = __float2bfloat16(e);
                        cst[row * 136 + (((col >> 3) ^ (row >> 3)) << 3) + (col & 7)] = pb;
                        rs += __bfloat162float(pb);
                    }
                    rs += __shfl_xor(rs, 1, 64);
                    rs += __shfl_xor(rs, 2, 64);
                    rs += __shfl_xor(rs, 4, 64);
                    rs += __shfl_xor(rs, 8, 64);
                    if ((lane & 15) == 0)
                        atomicAdd(&rowsum[(long)zb * rowsumStride + rowBase + row], rs);
                }
            }
        } else {
            #pragma unroll
            for (int mi = 0; mi < 4; ++mi) {
                #pragma unroll
                for (int ni = 0; ni < 4; ++ni) {
                    #pragma unroll
                    for (int r = 0; r < 4; ++r) {
                        const int row = wm + mi * 16 + crow0 + r;
                        const int col = wn + ni * 16 + ccol;
                        cst[row * 136 + (((col >> 3) ^ (row >> 3)) << 3) + (col & 7)] =
                            __float2bfloat16(acc[mi][ni][r] * scale);
                    }
                }
            }
        }
        __syncthreads();
        const int g   = tid & 15;
        const int r4  = tid >> 4;
        const int lof = ((g ^ r4) << 3);
        #pragma unroll
        for (int k = 0; k < 8; ++k) {
            const int row = r4 * 8 + k;
            const short8 v = *(const short8*)(cst + row * 136 + lof);
            *(short8*)(&((__hip_bfloat16*)C)[(long)(rowBase + row) * ldc + colBase + g * 8]) = v;
        }
    } else {
        // fp32 direct stores (Z partials)
        #pragma unroll
        for (int mi = 0; mi < 4; ++mi) {
            #pragma unroll
            for (int ni = 0; ni < 4; ++ni) {
                #pragma unroll
                for (int r = 0; r < 4; ++r) {
                    const int row = rowBase + wm + mi * 16 + crow0 + r;
                    const int col = colBase + wn + ni * 16 + ccol;
                    ((float*)C)[(long)row * ldc + col] = acc[mi][ni][r] * scale;
                }
            }
        }
    }
}

// ---------------------------------------------------------------------------
// Combine: Z = (Zp0 + Zp1) * (1/rowsum[row]).  Streaming, float4.
// ---------------------------------------------------------------------------
__global__ __launch_bounds__(256)
void combine_kernel(const float* __restrict__ Zp,
                    const float* __restrict__ rowsum,
                    float* __restrict__ Z, long partStride)
{
    const int i = blockIdx.x * 256 + threadIdx.x;   // float4 index
    const float4 a = ((const float4*)Zp)[i];
    const float4 b = ((const float4*)(Zp + partStride))[i];
    const float inv = 1.0f / rowsum[i >> 8];        // (4*i)/1024
    float4 o;
    o.x = (a.x + b.x) * inv;
    o.y = (a.y + b.y) * inv;
    o.z = (a.z + b.z) * inv;
    o.w = (a.w + b.w) * inv;
    ((float4*)Z)[i] = o;
}

// ---------------------------------------------------------------------------
extern "C" void kernel_launch(void* const* d_in, const int* in_sizes, int n_in,
                              void* d_out, int out_size, void* d_ws, size_t ws_size,
                              hipStream_t stream)
{
    constexpr int B = 4, L = 4096, DH = 1024, T = 1024, DG = 768, P = 256;

    const float* H  = (const float*)d_in[0];
    const float* G  = (const float*)d_in[1];
    const void*  mask = d_in[2];
    const float* Wk = (const float*)d_in[3];
    const float* Wq = (const float*)d_in[4];
    for (int i = 0; i < n_in; ++i) {
        switch (in_sizes[i]) {
            case B * L * DH: H    = (const float*)d_in[i]; break;
            case B * T * DG: G    = (const float*)d_in[i]; break;
            case B * L:      mask = d_in[i];               break;
            case P * DH:     Wk   = (const float*)d_in[i]; break;
            case P * DG:     Wq   = (const float*)d_in[i]; break;
        }
    }
    float* Z = (float*)d_out;

    char* ws = (char*)d_ws;
    __hip_bfloat16* Hbf  = (__hip_bfloat16*)ws;                      // [0, 32 MiB) — compact rows; dead after K-GEMM
    float*          Zp   = (float*)ws;                               // [0, 32 MiB): Zp0+Zp1 (over dead Hbf)
    __hip_bfloat16* Ht   = (__hip_bfloat16*)(ws + (32l << 20));      // [32, 64) — compact cols
    __hip_bfloat16* Gbf  = (__hip_bfloat16*)(ws + (64l << 20));      // [64, 70)
    __hip_bfloat16* Qbf  = (__hip_bfloat16*)(ws + (70l << 20));      // [70, 72)
    __hip_bfloat16* Kbf  = (__hip_bfloat16*)(ws + (72l << 20));      // [72, 80) — compact rows
    __hip_bfloat16* Wkbf = (__hip_bfloat16*)(ws + (80l << 20));      // 512 KiB
    __hip_bfloat16* Wqbf = (__hip_bfloat16*)(ws + (80l << 20) + (512l << 10)); // 384 KiB
    float*          rowsum    = (float*)(ws + (80l << 20) + (896l << 10));     // 64 KiB
    int*            widthFlag = (int*)  (ws + (80l << 20) + (960l << 10));     // 4 B
    int*            lcBuf     = (int*)  (ws + (80l << 20) + (961l << 10));     // 16 B
    int*            lcpadBuf  = (int*)  (ws + (80l << 20) + (961l << 10) + 64);// 16 B
    unsigned short* idxBuf    = (unsigned short*)(ws + (80l << 20) + (962l << 10)); // 32 KiB
    __hip_bfloat16* Sb   = (__hip_bfloat16*)(ws + (81l << 20));      // [81, 113) — compact cols

    constexpr long ZPART = (long)B * T * DH;   // 4,194,304 floats = 16 MiB

    const dim3 blk(256);

    // rowsum accumulates via atomics in the S-pass epilogue.
    hipMemsetAsync(rowsum, 0, (size_t)(B * T) * sizeof(float), stream);

    // w) mask width detection, then valid-l compaction scan
    mask_width_kernel<<<dim3(1), blk, 0, stream>>>((const unsigned char*)mask, widthFlag);
    mask_scan_kernel<<<dim3(B), blk, 0, stream>>>(mask, widthFlag, idxBuf, lcBuf, lcpadBuf, L);

    // 0) input prep (H gathered to compact index space)
    h_prep_kernel<<<dim3(L / 64, DH / 64, B), blk, 0, stream>>>(
        H, Hbf, Ht, idxBuf, lcBuf, lcpadBuf, L, DH);
    cvt_f32_bf16_kernel<<<dim3((P * DH) / 1024), blk, 0, stream>>>(Wk, (unsigned short*)Wkbf, (P * DH) / 4);
    cvt_f32_bf16_kernel<<<dim3((P * DG) / 1024), blk, 0, stream>>>(Wq, (unsigned short*)Wqbf, (P * DG) / 4);
    cvt_f32_bf16_kernel<<<dim3((B * T * DG) / 1024), blk, 0, stream>>>(G, (unsigned short*)Gbf, (B * T * DG) / 4);

    // 1) Q = G @ Wq^T   [B*T, P]
    gemm_bt_kernel<__hip_bfloat16, 1, 0, 0><<<dim3((B * T) / 128, P / 128, 1), blk, 0, stream>>>(
        Gbf, Wqbf, Qbf, DG, DG, DG, P, 0, 0, 0, 1.0f,
        nullptr, 0, 0, nullptr, nullptr, 0);
    // 2) K_c = Hbf_c @ Wk^T   compact rows; tiles >= lcpad exit
    gemm_bt_kernel<__hip_bfloat16, 1, 0, 1><<<dim3((B * L) / 128, P / 128, 1), blk, 0, stream>>>(
        Hbf, Wkbf, Kbf, DH, DH, DH, P, 0, 0, 0, 1.0f,
        nullptr, 0, 0, nullptr, lcpadBuf, L);
    // 3) P_c = exp(Q @ K_c^T / 16), cols >= lc zeroed; rowsum atomics
    gemm_bt_kernel<__hip_bfloat16, 1, 2, 2><<<dim3(T / 128, L / 128, B), blk, 0, stream>>>(
        Qbf, Kbf, Sb, P, P, P, L,
        (long)T * P, (long)L * P, (long)T * L, 0.0625f,
        rowsum, T, 0, lcBuf, lcpadBuf, L);
    // 4) Zp[kc] = P_c @ Ht_c^T   runtime K = lcpad[b], split-K x2, plain stores
    gemm_bt_kernel<float, 2, 0, 3><<<dim3(T / 128, DH / 128, B * 2), blk, 0, stream>>>(
        Sb, Ht, Zp, L, L, L, DH,
        (long)T * L, (long)DH * L, (long)T * DH, 1.0f,
        nullptr, 0, ZPART, nullptr, lcpadBuf, L);
    // 5) Z = (Zp0 + Zp1) / rowsum   streaming combine
    combine_kernel<<<dim3((B * T * DH / 4) / 256), blk, 0, stream>>>(
        Zp, rowsum, Z, ZPART);
}

// Round 7
// 219.893 us; speedup vs baseline: 1.4148x; 1.0904x over previous
//
#include <hip/hip_runtime.h>
#include <hip/hip_bf16.h>

// Problem: B=4, L=4096, DH=1024, T=1024, DG=768, P=256
// Inputs fp32 + bool mask (width auto-detect); OUTPUT fp32.
//
// MASK COMPACTION: ~50% of l are masked; masked columns have alpha == 0
// exactly. Prefix-scan builds per-batch valid-l list idx[b][c], Lc, Lc_pad.
// All passes work in compact index space (K/S/Z do ~half the work).
//
// LAUNCH-COUNT REDUCTION (round 7): 12 dispatches -> 6. ~90us of the round-6
// time was inter-dispatch gap (sum of kernel durations ~145us incl the
// harness's 41us/iter 256MiB workspace re-poison fill vs 239.8us measured).
//   1) scan_kernel:  width-detect + valid-l scan + rowsum zero   (was 3)
//   2) prep_all:     h_prep gather/transpose + cvt Wk/Wq/G       (was 4)
//   3) qk_gemm:      Q-GEMM and K-GEMM in one launch             (was 2)
//   4) S-GEMM   5) Z-GEMM   6) combine                           (unchanged)
//
// GEMM K-loop: COUNTED-VMCNT pipeline (T4), 3 LDS buffers, prefetch depth 2;
// GRANULE-XOR LDS swizzle (conflicts == 0, verified); bf16 epilogues via
// LDS-staged 16B/lane vectorized writeout; XCD-chunked blockIdx swizzle (T1).
// Z epilogue: plain fp32 stores (round-3 ablation: epilogue atomics were the
// bottleneck); split-K 2 (measured best) + streaming combine.

typedef __attribute__((ext_vector_type(8))) short short8;   // 8 bf16 = 4 VGPRs
typedef __attribute__((ext_vector_type(4))) float f32x4;

static __device__ __forceinline__ unsigned short bf16bits(float x) {
    __hip_bfloat16 b = __float2bfloat16(x);
    return *(unsigned short*)&b;
}

// Async global->LDS, 16 B per lane. LDS dest = wave-uniform base + lane*16.
static __device__ __forceinline__ void gload_lds16(const __hip_bfloat16* g,
                                                   __hip_bfloat16* l)
{
    auto gp = (const __attribute__((address_space(1))) unsigned int*)(uintptr_t)g;
    auto lp = (__attribute__((address_space(3))) unsigned int*)(unsigned int)(uintptr_t)l;
    __builtin_amdgcn_global_load_lds(gp, lp, 16, 0, 0);
}

// ---------------------------------------------------------------------------
// Fused: mask width detect (per-block, redundant) + valid-l compaction scan
// + rowsum zero. One block per batch.
// ---------------------------------------------------------------------------
__global__ __launch_bounds__(256)
void scan_kernel(const void* __restrict__ mask,
                 unsigned short* __restrict__ idx,
                 int* __restrict__ lc, int* __restrict__ lcpad,
                 float* __restrict__ rowsum, int L, int T, int B)
{
    const int b = blockIdx.x;
    const int tid = threadIdx.x;

    // zero this batch's rowsum slice (S-pass accumulates atomically)
    for (int i = tid; i < T; i += 256) rowsum[(long)b * T + i] = 0.f;

    // --- width detection over the whole mask buffer (B*L bools) ---
    const unsigned char*  m8g  = (const unsigned char*)mask;
    const unsigned short* m16g = (const unsigned short*)mask;
    const unsigned int*   m32g = (const unsigned int*)mask;
    __shared__ int c1, c2, c4, c8, cp, wsh;
    if (tid == 0) { c1 = c2 = c4 = c8 = cp = 0; }
    __syncthreads();
    {
        const int N = B * L;   // 16384
        int l1 = 0, l2 = 0, l4 = 0, l8 = 0, lp = 0;
        for (int i = tid; i < N; i += 256) l1 += (m8g[i] != 0);
        for (int i = tid; i < N / 2; i += 256) {
            l2 += (m16g[i] != 0);
            lp += ((m8g[2 * i] != 0) == (m8g[2 * i + 1] != 0));
        }
        for (int i = tid; i < N / 4; i += 256) l4 += (m32g[i] != 0);
        for (int i = tid; i < N / 8; i += 256) l8 += ((m32g[2 * i] | m32g[2 * i + 1]) != 0);
        atomicAdd(&c1, l1); atomicAdd(&c2, l2); atomicAdd(&c4, l4);
        atomicAdd(&c8, l8); atomicAdd(&cp, lp);
    }
    __syncthreads();
    if (tid == 0) {
        const float f1 = fabsf(c1 / 16384.f - 0.5f);
        const float f2 = fabsf(c2 / 8192.f  - 0.5f);
        const float f4 = fabsf(c4 / 4096.f  - 0.5f);
        const float f8 = fabsf(c8 / 2048.f  - 0.5f);
        int w = 1; float best = f1;
        if (f2 < best) { best = f2; w = 2; }
        if (f4 < best) { best = f4; w = 4; }
        if (f8 < best) { best = f8; w = 8; }
        if (w == 1 && cp > 7400) w = 2;
        wsh = w;
    }
    __syncthreads();
    const int w = wsh;

    // --- compaction scan for batch b (16 l's per thread) ---
    const unsigned char*  m8  = (const unsigned char*)mask;
    const unsigned short* m16 = (const unsigned short*)mask;
    const unsigned int*   m32 = (const unsigned int*)mask;
    const uint2*          m64 = (const uint2*)mask;
    bool v[16];
    int cnt = 0;
    #pragma unroll
    for (int i = 0; i < 16; ++i) {
        const int l = tid * 16 + i;
        const long mi = (long)b * L + l;
        bool masked;
        if (w == 1)      masked = m8[mi] != 0;
        else if (w == 2) masked = m16[mi] != 0;
        else if (w == 4) masked = m32[mi] != 0;
        else             { uint2 q = m64[mi]; masked = (q.x | q.y) != 0; }
        v[i] = !masked;
        cnt += v[i] ? 1 : 0;
    }
    __shared__ int waveTot[4];
    int pre = cnt;
    #pragma unroll
    for (int off = 1; off < 64; off <<= 1) {
        const int t = __shfl_up(pre, off, 64);
        if ((tid & 63) >= off) pre += t;
    }
    if ((tid & 63) == 63) waveTot[tid >> 6] = pre;
    __syncthreads();
    int waveOff = 0;
    for (int wv = 0; wv < (tid >> 6); ++wv) waveOff += waveTot[wv];
    int o = waveOff + pre - cnt;          // exclusive prefix for this thread
    #pragma unroll
    for (int i = 0; i < 16; ++i)
        if (v[i]) idx[(long)b * L + (o++)] = (unsigned short)(tid * 16 + i);
    if (tid == 255) {
        const int total = waveOff + pre;
        lc[b] = total;
        lcpad[b] = (total + 127) & ~127;
    }
}

// ---------------------------------------------------------------------------
// Fused prep: blocks [0, 4096) = H gather/convert/transpose (64x64 tiles);
// blocks [4096, 7616) = fp32->bf16 cvt for Wk (256), Wq (192), G (3072).
// ---------------------------------------------------------------------------
__global__ __launch_bounds__(256)
void prep_all_kernel(const float* __restrict__ H,
                     __hip_bfloat16* __restrict__ Hbf,
                     __hip_bfloat16* __restrict__ Ht,
                     const unsigned short* __restrict__ idx,
                     const int* __restrict__ lc, const int* __restrict__ lcpad,
                     const float* __restrict__ Wk, unsigned short* __restrict__ Wkbf,
                     const float* __restrict__ Wq, unsigned short* __restrict__ Wqbf,
                     const float* __restrict__ G,  unsigned short* __restrict__ Gbf,
                     int L, int D)
{
    __shared__ __align__(16) __hip_bfloat16 tile[64][72];  // [d][c], pad 8
    int id = blockIdx.x;
    if (id < 4096) {
        // --- h_prep gather: c-tile (id&63), d-tile ((id>>6)&15), b (id>>10) ---
        const int b  = id >> 10;
        const int c0 = (id & 63) * 64;
        if (c0 >= lcpad[b]) return;       // uniform: beyond padded extent
        const int d0 = ((id >> 6) & 15) * 64;
        const int Lcb = lc[b];
        const float* Hb = H + (long)b * L * D;
        __hip_bfloat16* Hbfb = Hbf + (long)b * L * D;
        __hip_bfloat16* Htb  = Ht  + (long)b * D * L;
        const int tx = threadIdx.x & 15, ty = threadIdx.x >> 4;  // 16 x 16
        #pragma unroll
        for (int p = 0; p < 4; ++p) {
            const int row = ty + p * 16;     // compact index within tile
            const int c = c0 + row;
            float4 v = {0.f, 0.f, 0.f, 0.f};
            if (c < Lcb) {
                const int l = idx[(long)b * L + c];
                v = *(const float4*)(&Hb[(long)l * D + d0 + tx * 4]);
            }
            ushort4 o;
            o.x = bf16bits(v.x); o.y = bf16bits(v.y);
            o.z = bf16bits(v.z); o.w = bf16bits(v.w);
            *(ushort4*)(&Hbfb[(long)c * D + d0 + tx * 4]) = o;
            tile[tx * 4 + 0][row] = __float2bfloat16(v.x);
            tile[tx * 4 + 1][row] = __float2bfloat16(v.y);
            tile[tx * 4 + 2][row] = __float2bfloat16(v.z);
            tile[tx * 4 + 3][row] = __float2bfloat16(v.w);
        }
        __syncthreads();
        const int ll = threadIdx.x & 7;      // 8 threads x 16B = 128B per d-row
        const int dq = threadIdx.x >> 3;     // 32 d-rows per pass
        #pragma unroll
        for (int q = 0; q < 2; ++q) {
            const int dd = dq + q * 32;
            const short8 v = *(const short8*)(&tile[dd][ll * 8]);
            *(short8*)(&Htb[(long)(d0 + dd) * L + c0 + ll * 8]) = v;
        }
        return;
    }
    // --- cvt ranges ---
    id -= 4096;
    const float* in; unsigned short* out; int n4;
    if (id < 256)       { in = Wk; out = Wkbf; n4 = (256 * 1024) / 4; }
    else if (id < 448)  { id -= 256; in = Wq; out = Wqbf; n4 = (256 * 768) / 4; }
    else                { id -= 448; in = G;  out = Gbf;  n4 = (4 * 1024 * 768) / 4; }
    const int i = id * 256 + threadIdx.x;
    if (i >= n4) return;
    float4 v = ((const float4*)in)[i];
    ushort4 o;
    o.x = bf16bits(v.x); o.y = bf16bits(v.y);
    o.z = bf16bits(v.z); o.w = bf16bits(v.w);
    ((ushort4*)out)[i] = o;
}

// ---------------------------------------------------------------------------
// GEMM body: C[M,N] (op)= scale * A[M,K] @ Bm[N,K]^T  (bf16 row-major)
// 128x128 tile, 4 waves, wave 64x64 via 4x4 MFMA 16x16x32 bf16.
// Counted-vmcnt 3-buffer pipeline; lds_pool (48 KiB, hoisted to the wrapper)
// reused for the bf16 epilogue writeout.
// MODE 0: plain store. bf16 -> LDS-staged vectorized writeout; f32 ->
//         direct stores at kc*partStride (Z partials).
// MODE 2: P = exp(scale*acc); cols >= lc[zb] -> 0 (compare, no mask loads);
//         bf16 via LDS writeout; fp32 row-sum atomics (bf16-rounded values).
// CMODE 0: none. 1: row-limit exit. 2: col-limit exit. 3: runtime K=lcpad[zb].
// ---------------------------------------------------------------------------
template <typename OutT, int SPLITK, int MODE, int CMODE>
static __device__ __forceinline__
void gemm_bt_body(int bx, int by, int bz, __hip_bfloat16* lds_pool,
                  const __hip_bfloat16* __restrict__ A,
                  const __hip_bfloat16* __restrict__ Bm,
                  OutT* __restrict__ C,
                  int K, int lda, int ldb, int ldc,
                  long batchStrideA, long batchStrideB, long batchStrideC,
                  float scale,
                  float* __restrict__ rowsum, int rowsumStride,
                  long partStride,
                  const int* __restrict__ lc, const int* __restrict__ lcpad,
                  int Lfull)
{
    const int zb = bz / SPLITK;
    const int kc = bz % SPLITK;
    const int rowBase = bx * 128;
    const int colBase = by * 128;

    if constexpr (CMODE == 1) {          // K-GEMM: skip masked-out row tiles
        const int bb = rowBase / Lfull;
        if (rowBase - bb * Lfull >= lcpad[bb]) return;
    }
    if constexpr (CMODE == 2) {          // S-GEMM: skip masked-out col tiles
        if (colBase >= lcpad[zb]) return;
    }

    A  += (long)zb * batchStrideA;
    Bm += (long)zb * batchStrideB;
    C  += (long)zb * batchStrideC + (long)kc * partStride;
    int Kdyn = K;
    if constexpr (CMODE == 3) Kdyn = lcpad[zb];   // Z-GEMM: compacted K
    const int Kloc  = Kdyn / SPLITK;
    const int kbase = kc * Kloc;
    const int NT    = Kloc / 32;          // k-tiles (>= 2: lcpad >= 128)

    const int tid  = threadIdx.x;
    const int lane = tid & 63;
    const int wave = tid >> 6;
    const int wm = (wave & 1) * 64;
    const int wn = (wave >> 1) * 64;

    __hip_bfloat16* AsP = lds_pool;            // buf*4096 + row*32 + col
    __hip_bfloat16* BsP = lds_pool + 12288;

    f32x4 acc[4][4];
    #pragma unroll
    for (int i = 0; i < 4; ++i)
        #pragma unroll
        for (int j = 0; j < 4; ++j)
            acc[i][j] = (f32x4){0.f, 0.f, 0.f, 0.f};

    // Staging: wave w covers rows [w*32, w*32+32) as two 16-row x 1024 B chunks.
    // Lane i: LDS lands at (row = i>>2, granule g = i&3). Pre-swizzle the
    // GLOBAL source granule: q = g ^ ((row>>1)&3)  (involution per row).
    const int srow = lane >> 2;
    const int scol = ((lane & 3) ^ ((lane >> 3) & 3)) * 8;   // swizzled source col
    const long ar0 = (long)(rowBase + wave * 32 + srow) * lda;
    const long ar1 = ar0 + 16l * lda;
    const long br0 = (long)(colBase + wave * 32 + srow) * ldb;
    const long br1 = br0 + 16l * ldb;

    const int mrow = lane & 15;         // fragment m/n index
    // Swizzled fragment k-offset (row bases ≡0 mod 16 -> lane-only term).
    const int koff = (((lane >> 4) ^ ((lane >> 1) & 3)) * 8);

    // Per wave each tile issues EXACTLY 4 global_load_lds ops (vmcnt units).
    auto stage = [&](int buf, int t) {
        const int kk = kbase + t * 32 + scol;
        gload_lds16(A  + ar0 + kk, AsP + buf * 4096 + wave * 1024);
        gload_lds16(A  + ar1 + kk, AsP + buf * 4096 + wave * 1024 + 512);
        gload_lds16(Bm + br0 + kk, BsP + buf * 4096 + wave * 1024);
        gload_lds16(Bm + br1 + kk, BsP + buf * 4096 + wave * 1024 + 512);
    };

    // Prologue: tiles 0,1 in flight (8 vmcnt ops/wave). No barrier yet.
    stage(0, 0);
    if (NT > 1) stage(1, 1);

    int cur = 0;
    for (int t = 0; t < NT; ++t) {
        // Drain OWN tile-t loads only; tile t+1 stays in flight across the
        // barrier (counted vmcnt — never drain to 0 in the main loop).
        if (t + 1 < NT)
            asm volatile("s_waitcnt vmcnt(4)" ::: "memory");
        else
            asm volatile("s_waitcnt vmcnt(0)" ::: "memory");
        __builtin_amdgcn_s_barrier();
        if (t + 2 < NT) {
            const int nxt2 = (cur >= 1) ? cur - 1 : cur + 2;   // (cur+2)%3
            stage(nxt2, t + 2);
        }

        short8 af[4], bf[4];
        #pragma unroll
        for (int mi = 0; mi < 4; ++mi)
            af[mi] = *(const short8*)(AsP + cur * 4096 + (wm + mi * 16 + mrow) * 32 + koff);
        #pragma unroll
        for (int ni = 0; ni < 4; ++ni)
            bf[ni] = *(const short8*)(BsP + cur * 4096 + (wn + ni * 16 + mrow) * 32 + koff);

        #pragma unroll
        for (int mi = 0; mi < 4; ++mi)
            #pragma unroll
            for (int ni = 0; ni < 4; ++ni)
                acc[mi][ni] = __builtin_amdgcn_mfma_f32_16x16x32_bf16(
                    af[mi], bf[ni], acc[mi][ni], 0, 0, 0);
        cur = (cur == 2) ? 0 : cur + 1;
    }

    // C/D layout (verified m89/m91): col = lane&15, row = (lane>>4)*4 + r
    const int crow0 = (lane >> 4) * 4;
    const int ccol  = lane & 15;

    if constexpr (MODE == 2 || sizeof(OutT) == 2) {
        // --- bf16 LDS-staged vectorized writeout ---
        __syncthreads();                   // pool safe: vmcnt(0) drained above
        __hip_bfloat16* cst = lds_pool;    // [128][136], granule^(row>>3)

        if constexpr (MODE == 2) {
            const int lcv = lc[zb];        // valid-col limit (compare, no loads)
            bool mk[4];
            #pragma unroll
            for (int ni = 0; ni < 4; ++ni)
                mk[ni] = (colBase + wn + ni * 16 + ccol) >= lcv;
            #pragma unroll
            for (int mi = 0; mi < 4; ++mi) {
                #pragma unroll
                for (int r = 0; r < 4; ++r) {
                    const int row = wm + mi * 16 + crow0 + r;
                    float rs = 0.f;
                    #pragma unroll
                    for (int ni = 0; ni < 4; ++ni) {
                        const int col = wn + ni * 16 + ccol;
                        const float e = mk[ni] ? 0.f
                                               : __expf(acc[mi][ni][r] * scale);
                        const __hip_bfloat16 pb = __float2bfloat16(e);
                        cst[row * 136 + (((col >> 3) ^ (row >> 3)) << 3) + (col & 7)] = pb;
                        rs += __bfloat162float(pb);
                    }
                    rs += __shfl_xor(rs, 1, 64);
                    rs += __shfl_xor(rs, 2, 64);
                    rs += __shfl_xor(rs, 4, 64);
                    rs += __shfl_xor(rs, 8, 64);
                    if ((lane & 15) == 0)
                        atomicAdd(&rowsum[(long)zb * rowsumStride + rowBase + row], rs);
                }
            }
        } else {
            #pragma unroll
            for (int mi = 0; mi < 4; ++mi) {
                #pragma unroll
                for (int ni = 0; ni < 4; ++ni) {
                    #pragma unroll
                    for (int r = 0; r < 4; ++r) {
                        const int row = wm + mi * 16 + crow0 + r;
                        const int col = wn + ni * 16 + ccol;
                        cst[row * 136 + (((col >> 3) ^ (row >> 3)) << 3) + (col & 7)] =
                            __float2bfloat16(acc[mi][ni][r] * scale);
                    }
                }
            }
        }
        __syncthreads();
        const int g   = tid & 15;
        const int r4  = tid >> 4;
        const int lof = ((g ^ r4) << 3);
        #pragma unroll
        for (int k = 0; k < 8; ++k) {
            const int row = r4 * 8 + k;
            const short8 v = *(const short8*)(cst + row * 136 + lof);
            *(short8*)(&((__hip_bfloat16*)C)[(long)(rowBase + row) * ldc + colBase + g * 8]) = v;
        }
    } else {
        // fp32 direct stores (Z partials)
        #pragma unroll
        for (int mi = 0; mi < 4; ++mi) {
            #pragma unroll
            for (int ni = 0; ni < 4; ++ni) {
                #pragma unroll
                for (int r = 0; r < 4; ++r) {
                    const int row = rowBase + wm + mi * 16 + crow0 + r;
                    const int col = colBase + wn + ni * 16 + ccol;
                    ((float*)C)[(long)row * ldc + col] = acc[mi][ni][r] * scale;
                }
            }
        }
    }
}

// XCD-chunked swizzle (T1): remap so each XCD owns a contiguous grid chunk.
static __device__ __forceinline__ void xcd_swizzle(int& bx, int& by, int& bz)
{
    const int nwg = gridDim.x * gridDim.y * gridDim.z;
    bx = blockIdx.x; by = blockIdx.y; bz = blockIdx.z;
    if ((nwg & 7) == 0) {
        int lin = bx + gridDim.x * (by + gridDim.y * bz);
        lin = (lin & 7) * (nwg >> 3) + (lin >> 3);
        bx = lin % gridDim.x;
        const int t = lin / gridDim.x;
        by = t % gridDim.y;
        bz = t / gridDim.y;
    }
}

template <typename OutT, int SPLITK, int MODE, int CMODE>
__global__ __launch_bounds__(256)
void gemm_bt_kernel(const __hip_bfloat16* __restrict__ A,
                    const __hip_bfloat16* __restrict__ Bm,
                    OutT* __restrict__ C,
                    int K, int lda, int ldb, int ldc,
                    long batchStrideA, long batchStrideB, long batchStrideC,
                    float scale,
                    float* __restrict__ rowsum, int rowsumStride,
                    long partStride,
                    const int* __restrict__ lc, const int* __restrict__ lcpad,
                    int Lfull)
{
    __shared__ __align__(16) __hip_bfloat16 lds_pool[24576];
    int bx, by, bz;
    xcd_swizzle(bx, by, bz);
    gemm_bt_body<OutT, SPLITK, MODE, CMODE>(bx, by, bz, lds_pool,
        A, Bm, C, K, lda, ldb, ldc, batchStrideA, batchStrideB, batchStrideC,
        scale, rowsum, rowsumStride, partStride, lc, lcpad, Lfull);
}

// ---------------------------------------------------------------------------
// Merged Q-GEMM + K-GEMM launch. Grid (160, 2, 1):
//   bx <  32: Q = Gbf @ Wq^T  [B*T=4096 rows, K=DG=768]
//   bx >= 32: K = Hbf_c @ Wk^T [B*L rows cap, K=DH=1024], row-tiles >= lcpad exit
// ---------------------------------------------------------------------------
__global__ __launch_bounds__(256)
void qk_gemm_kernel(const __hip_bfloat16* __restrict__ Gbf,
                    const __hip_bfloat16* __restrict__ Wqbf,
                    __hip_bfloat16* __restrict__ Qbf,
                    const __hip_bfloat16* __restrict__ Hbf,
                    const __hip_bfloat16* __restrict__ Wkbf,
                    __hip_bfloat16* __restrict__ Kbf,
                    const int* __restrict__ lcpad,
                    int DG_, int DH_, int P_, int L_)
{
    __shared__ __align__(16) __hip_bfloat16 lds_pool[24576];
    int bx, by, bz;
    xcd_swizzle(bx, by, bz);
    if (bx < 32) {
        gemm_bt_body<__hip_bfloat16, 1, 0, 0>(bx, by, 0, lds_pool,
            Gbf, Wqbf, Qbf, DG_, DG_, DG_, P_, 0, 0, 0, 1.0f,
            nullptr, 0, 0, nullptr, nullptr, 0);
    } else {
        gemm_bt_body<__hip_bfloat16, 1, 0, 1>(bx - 32, by, 0, lds_pool,
            Hbf, Wkbf, Kbf, DH_, DH_, DH_, P_, 0, 0, 0, 1.0f,
            nullptr, 0, 0, nullptr, lcpad, L_);
    }
}

// ---------------------------------------------------------------------------
// Combine: Z = (Zp0 + Zp1) * (1/rowsum[row]).  Streaming, float4.
// ---------------------------------------------------------------------------
__global__ __launch_bounds__(256)
void combine_kernel(const float* __restrict__ Zp,
                    const float* __restrict__ rowsum,
                    float* __restrict__ Z, long partStride)
{
    const int i = blockIdx.x * 256 + threadIdx.x;   // float4 index
    const float4 a = ((const float4*)Zp)[i];
    const float4 b = ((const float4*)(Zp + partStride))[i];
    const float inv = 1.0f / rowsum[i >> 8];        // (4*i)/1024
    float4 o;
    o.x = (a.x + b.x) * inv;
    o.y = (a.y + b.y) * inv;
    o.z = (a.z + b.z) * inv;
    o.w = (a.w + b.w) * inv;
    ((float4*)Z)[i] = o;
}

// ---------------------------------------------------------------------------
extern "C" void kernel_launch(void* const* d_in, const int* in_sizes, int n_in,
                              void* d_out, int out_size, void* d_ws, size_t ws_size,
                              hipStream_t stream)
{
    constexpr int B = 4, L = 4096, DH = 1024, T = 1024, DG = 768, P = 256;

    const float* H  = (const float*)d_in[0];
    const float* G  = (const float*)d_in[1];
    const void*  mask = d_in[2];
    const float* Wk = (const float*)d_in[3];
    const float* Wq = (const float*)d_in[4];
    for (int i = 0; i < n_in; ++i) {
        switch (in_sizes[i]) {
            case B * L * DH: H    = (const float*)d_in[i]; break;
            case B * T * DG: G    = (const float*)d_in[i]; break;
            case B * L:      mask = d_in[i];               break;
            case P * DH:     Wk   = (const float*)d_in[i]; break;
            case P * DG:     Wq   = (const float*)d_in[i]; break;
        }
    }
    float* Z = (float*)d_out;

    char* ws = (char*)d_ws;
    __hip_bfloat16* Hbf  = (__hip_bfloat16*)ws;                      // [0, 32 MiB) — compact rows; dead after K-GEMM
    float*          Zp   = (float*)ws;                               // [0, 32 MiB): Zp0+Zp1 (over dead Hbf)
    __hip_bfloat16* Ht   = (__hip_bfloat16*)(ws + (32l << 20));      // [32, 64) — compact cols
    __hip_bfloat16* Gbf  = (__hip_bfloat16*)(ws + (64l << 20));      // [64, 70)
    __hip_bfloat16* Qbf  = (__hip_bfloat16*)(ws + (70l << 20));      // [70, 72)
    __hip_bfloat16* Kbf  = (__hip_bfloat16*)(ws + (72l << 20));      // [72, 80) — compact rows
    __hip_bfloat16* Wkbf = (__hip_bfloat16*)(ws + (80l << 20));      // 512 KiB
    __hip_bfloat16* Wqbf = (__hip_bfloat16*)(ws + (80l << 20) + (512l << 10)); // 384 KiB
    float*          rowsum    = (float*)(ws + (80l << 20) + (896l << 10));     // 64 KiB
    int*            lcBuf     = (int*)  (ws + (80l << 20) + (961l << 10));     // 16 B
    int*            lcpadBuf  = (int*)  (ws + (80l << 20) + (961l << 10) + 64);// 16 B
    unsigned short* idxBuf    = (unsigned short*)(ws + (80l << 20) + (962l << 10)); // 32 KiB
    __hip_bfloat16* Sb   = (__hip_bfloat16*)(ws + (81l << 20));      // [81, 113) — compact cols

    constexpr long ZPART = (long)B * T * DH;   // 4,194,304 floats = 16 MiB

    const dim3 blk(256);

    // 1) width + valid-l scan + rowsum zero
    scan_kernel<<<dim3(B), blk, 0, stream>>>(
        mask, idxBuf, lcBuf, lcpadBuf, rowsum, L, T, B);

    // 2) fused prep: H gather/transpose (4096 blocks) + cvt Wk/Wq/G (3520)
    prep_all_kernel<<<dim3(7616), blk, 0, stream>>>(
        H, Hbf, Ht, idxBuf, lcBuf, lcpadBuf,
        Wk, (unsigned short*)Wkbf, Wq, (unsigned short*)Wqbf,
        G, (unsigned short*)Gbf, L, DH);

    // 3) Q = G @ Wq^T  and  K_c = Hbf_c @ Wk^T  in one launch
    qk_gemm_kernel<<<dim3(160, 2, 1), blk, 0, stream>>>(
        Gbf, Wqbf, Qbf, Hbf, Wkbf, Kbf, lcpadBuf, DG, DH, P, L);

    // 4) P_c = exp(Q @ K_c^T / 16), cols >= lc zeroed; rowsum atomics
    gemm_bt_kernel<__hip_bfloat16, 1, 2, 2><<<dim3(T / 128, L / 128, B), blk, 0, stream>>>(
        Qbf, Kbf, Sb, P, P, P, L,
        (long)T * P, (long)L * P, (long)T * L, 0.0625f,
        rowsum, T, 0, lcBuf, lcpadBuf, L);
    // 5) Zp[kc] = P_c @ Ht_c^T   runtime K = lcpad[b], split-K x2, plain stores
    gemm_bt_kernel<float, 2, 0, 3><<<dim3(T / 128, DH / 128, B * 2), blk, 0, stream>>>(
        Sb, Ht, Zp, L, L, L, DH,
        (long)T * L, (long)DH * L, (long)T * DH, 1.0f,
        nullptr, 0, ZPART, nullptr, lcpadBuf, L);
    // 6) Z = (Zp0 + Zp1) / rowsum   streaming combine
    combine_kernel<<<dim3((B * T * DH / 4) / 256), blk, 0, stream>>>(
        Zp, rowsum, Z, ZPART);
}